// Round 1
// baseline (7475.614 us; speedup 1.0000x reference)
//
#include <hip/hip_runtime.h>

#define NB 2
#define NN 16384
#define NC 256
#define NPp 2048
#define NSs 32
#define NH 4
#define HDh 64
#define NL 2
#define NDFF 512
#define LFv (NPp*NSs)
#define LNEPS 1e-5f

typedef short s16x8 __attribute__((ext_vector_type(8)));
typedef float f32x4 __attribute__((ext_vector_type(4)));
typedef unsigned short u16;

__device__ __forceinline__ u16 f2bf(float f){
  unsigned u = __float_as_uint(f);
  u += 0x7fffu + ((u>>16)&1u);
  return (u16)(u>>16);
}

__device__ __forceinline__ f32x4 mfma16(s16x8 a, s16x8 b, f32x4 c){
  return __builtin_amdgcn_mfma_f32_16x16x32_bf16(a, b, c, 0, 0, 0);
}

// ---------------- prep: bf16 weights, first[] init, bn fold ----------------
__global__ void k_prep(const float* __restrict__ ipw, const float* __restrict__ opw,
                       const float* __restrict__ fc1w, const float* __restrict__ fc2w,
                       const float* __restrict__ pe2w,
                       const float* __restrict__ bng, const float* __restrict__ bnb,
                       const float* __restrict__ bnm, const float* __restrict__ bnv,
                       u16* ipwb, u16* opwb, u16* fc1wb, u16* fc2wb, u16* pe2wb,
                       float* bnsc, float* bnsh, int* first){
  const int i0 = blockIdx.x*blockDim.x + threadIdx.x;
  const int stride = gridDim.x*blockDim.x;
  for (int i=i0; i<NL*768*NC; i+=stride) ipwb[i] = f2bf(ipw[i]);
  for (int i=i0; i<NL*NC*NC; i+=stride)  opwb[i] = f2bf(opw[i]);
  for (int i=i0; i<NL*NDFF*NC; i+=stride) fc1wb[i] = f2bf(fc1w[i]);
  for (int i=i0; i<NL*NC*NDFF; i+=stride) fc2wb[i] = f2bf(fc2w[i]);
  for (int i=i0; i<NC*128; i+=stride)    pe2wb[i] = f2bf(pe2w[i]);
  for (int i=i0; i<NB*NN; i+=stride)     first[i] = LFv;
  for (int i=i0; i<128; i+=stride){
    float sc = bng[i]*rsqrtf(bnv[i]+LNEPS);
    bnsc[i] = sc; bnsh[i] = bnb[i] - bnm[i]*sc;
  }
}

// ---------------- FPS: one block per batch, sequential 2047 steps ----------
__global__ __launch_bounds__(1024,1) void k_fps(const float* __restrict__ xyz,
                                                int* fps_idx, float* newxyz){
#pragma clang fp contract(off)
  const int b = blockIdx.x;
  const int t = threadIdx.x;
  const float* xb = xyz + (size_t)b*NN*3;
  float px[16], py[16], pz[16], dd[16];
  #pragma unroll
  for (int j=0;j<16;j++){
    int i = t + j*1024;
    px[j]=xb[i*3]; py[j]=xb[i*3+1]; pz[j]=xb[i*3+2];
    dd[j]=1e10f;
  }
  __shared__ float c3[3];
  __shared__ float wmax[16];
  __shared__ float bmax_s;
  __shared__ int winner;
  if (t==0){
    c3[0]=px[0]; c3[1]=py[0]; c3[2]=pz[0];
    winner = 0x7fffffff;
    fps_idx[b*NPp] = 0;
    newxyz[(size_t)b*NPp*3+0]=px[0]; newxyz[(size_t)b*NPp*3+1]=py[0]; newxyz[(size_t)b*NPp*3+2]=pz[0];
  }
  __syncthreads();
  for (int step=1; step<NPp; ++step){
    const float cx=c3[0], cy=c3[1], cz=c3[2];
    float lm = -1.f;
    #pragma unroll
    for (int j=0;j<16;j++){
      float dx=px[j]-cx, dy=py[j]-cy, dz=pz[j]-cz;
      float d2=(dx*dx+dy*dy)+dz*dz;
      float dn = fminf(dd[j], d2);
      dd[j]=dn;
      lm = fmaxf(lm, dn);
    }
    #pragma unroll
    for (int m=1;m<64;m<<=1) lm = fmaxf(lm, __shfl_xor(lm, m));
    if ((t&63)==0) wmax[t>>6]=lm;
    __syncthreads();                                   // (A)
    if (t<16){
      float v = wmax[t];
      #pragma unroll
      for (int m=1;m<16;m<<=1) v = fmaxf(v, __shfl_xor(v, m));
      if (t==0) bmax_s = v;
    }
    __syncthreads();                                   // (B)
    const float M = bmax_s;
    int li = 0x7fffffff;
    #pragma unroll
    for (int j=0;j<16;j++) if (dd[j]==M){ int i=t+j*1024; li = (i<li)?i:li; }
    #pragma unroll
    for (int m=1;m<64;m<<=1){ int o=__shfl_xor(li, m); li = (o<li)?o:li; }
    if ((t&63)==0 && li != 0x7fffffff) atomicMin(&winner, li);
    __syncthreads();                                   // (C)
    const int w = winner;
    if (t == (w & 1023)){
      #pragma unroll
      for (int j=0;j<16;j++) if ((t + j*1024) == w){ c3[0]=px[j]; c3[1]=py[j]; c3[2]=pz[j]; }
      fps_idx[b*NPp + step] = w;
      newxyz[((size_t)b*NPp+step)*3+0]=c3[0];
      newxyz[((size_t)b*NPp+step)*3+1]=c3[1];
      newxyz[((size_t)b*NPp+step)*3+2]=c3[2];
    }
    __syncthreads();                                   // (D)
    if (t==0) winner = 0x7fffffff;
  }
}

// ---------------- ball query: one wave per center ---------------------------
__global__ __launch_bounds__(256) void k_ballq(const float* __restrict__ xyz,
                                               const float* __restrict__ newxyz,
                                               int* __restrict__ idxg){
#pragma clang fp contract(off)
  const int gw = (blockIdx.x*256 + threadIdx.x) >> 6;
  const int lane = threadIdx.x & 63;
  if (gw >= NB*NPp) return;
  const int b = gw / NPp;
  const float cx=newxyz[(size_t)gw*3], cy=newxyz[(size_t)gw*3+1], cz=newxyz[(size_t)gw*3+2];
  const float* xb = xyz + (size_t)b*NN*3;
  int* op = idxg + (size_t)gw*NSs;
  int count = 0;
  int first_i = 0;
  for (int base=0; base<NN; base+=64){
    const int i = base + lane;
    float dx=xb[i*3]-cx, dy=xb[i*3+1]-cy, dz=xb[i*3+2]-cz;
    float d2=(dx*dx+dy*dy)+dz*dz;
    bool hit = d2 < 1.0f;
    unsigned long long m = __ballot(hit);
    if (m){
      int rank = __popcll(m & ((1ull<<lane)-1ull));
      int slot = count + rank;
      if (hit && slot < NSs) op[slot] = i;
      if (count == 0) first_i = base + (__ffsll((unsigned long long)m)-1);
      count += __popcll(m);
      if (count >= NSs) break;
    }
  }
  if (count < NSs){
    if (lane >= count && lane < NSs) op[lane] = (count>0) ? first_i : 0;
  }
}

// ---------------- first-occurrence (segment_min of flat pos) ---------------
__global__ void k_first(const int* __restrict__ idxg, int* __restrict__ first){
  int i = blockIdx.x*blockDim.x + threadIdx.x;
  if (i < NB*NPp*NSs){
    int b = i / (NPp*NSs);
    int pos = i % (NPp*NSs);
    atomicMin(&first[b*NN + idxg[i]], pos);
  }
}

// ---------------- transpose features -> out (non-winners) + featT ----------
__global__ __launch_bounds__(256) void k_outinit(const float* __restrict__ feat,
                                                 const int* __restrict__ first,
                                                 float* __restrict__ out,
                                                 float* __restrict__ featT, int useT){
  __shared__ float T[32][33];
  const int b = blockIdx.y;
  const int n0 = blockIdx.x*32;
  const int t = threadIdx.x;
  const int tn = t & 31, tc = t >> 5;          // tc in 0..7
  for (int cb=0; cb<NC; cb+=32){
    #pragma unroll
    for (int i=0;i<32;i+=8)
      T[tc+i][tn] = feat[((size_t)b*NC + cb+tc+i)*NN + n0+tn];
    __syncthreads();
    #pragma unroll
    for (int i=0;i<32;i+=8){
      int n = n0 + tc + i;
      float v = T[tn][tc+i];
      if (useT) featT[((size_t)b*NN + n)*NC + cb+tn] = v;
      if (first[b*NN+n] == LFv) out[((size_t)b*NN + n)*NC + cb+tn] = v;
    }
    __syncthreads();
  }
}

// ---------------- fused group + PE + 2-layer transformer + scatter ---------
__device__ __forceinline__ void ln_block(float (*xs)[NC], u16 (*xn)[264],
                                         const float* __restrict__ s_,
                                         const float* __restrict__ b_, int t){
  const int s = t >> 3, j = t & 7;            // 8 threads per row
  float v[32];
  float sum = 0.f;
  #pragma unroll
  for (int k=0;k<32;k++){ v[k]=xs[s][j*32+k]; sum += v[k]; }
  #pragma unroll
  for (int m=1;m<8;m<<=1) sum += __shfl_xor(sum, m);
  const float mean = sum * (1.f/256.f);
  float vs = 0.f;
  #pragma unroll
  for (int k=0;k<32;k++){ float d=v[k]-mean; vs += d*d; }
  #pragma unroll
  for (int m=1;m<8;m<<=1) vs += __shfl_xor(vs, m);
  const float rstd = rsqrtf(vs*(1.f/256.f) + LNEPS);
  #pragma unroll
  for (int k=0;k<32;k++){
    int c = j*32+k;
    float y = (v[k]-mean)*rstd*s_[c] + b_[c];
    xs[s][c] = y;
    xn[s][c] = f2bf(y);
  }
}

__global__ __launch_bounds__(256,1) void k_tf(
    const float* __restrict__ xyz, const float* __restrict__ features,
    const float* __restrict__ featT, int useT,
    const int* __restrict__ idxg, const float* __restrict__ newxyz,
    const int* __restrict__ firstg,
    const float* __restrict__ pe1w, const float* __restrict__ pe1b,
    const float* __restrict__ bnsc, const float* __restrict__ bnsh,
    const u16* __restrict__ pe2wb, const float* __restrict__ pe2b,
    const u16* __restrict__ ipwb, const float* __restrict__ ipb,
    const u16* __restrict__ opwb, const float* __restrict__ opb,
    const float* __restrict__ ln1s, const float* __restrict__ ln1b,
    const float* __restrict__ ln2s, const float* __restrict__ ln2b,
    const u16* __restrict__ fc1wb, const float* __restrict__ fc1b,
    const u16* __restrict__ fc2wb, const float* __restrict__ fc2b,
    float* __restrict__ out){
  __shared__ float xs[32][NC];        // residual stream (fp32)
  __shared__ u16  xn[32][264];        // LN output / attn-out (bf16, A operand)
  __shared__ u16  qb[32][776];        // qkv (bf16), reused as FF hidden
  __shared__ u16  pb[NH][32][40];     // softmax P per head
  __shared__ int  idx_sh[32];
  __shared__ float gx_sh[32][3];

  const int seq = blockIdx.x;
  const int b = seq / NPp, p = seq % NPp;
  const int t = threadIdx.x, lane = t & 63, wid = t >> 6;
  const int c15 = lane & 15, g4 = lane >> 4;

  if (t < 32) idx_sh[t] = idxg[(size_t)seq*NSs + t];
  __syncthreads();
  if (t < 96){
    int s = t/3, d = t%3;
    gx_sh[s][d] = xyz[((size_t)b*NN + idx_sh[s])*3 + d] - newxyz[(size_t)seq*3 + d];
  }
  if (useT){
    for (int s=0;s<32;s++) xs[s][t] = featT[((size_t)b*NN + idx_sh[s])*NC + t];
  } else {
    for (int s=0;s<32;s++) xs[s][t] = features[((size_t)b*NC + t)*NN + idx_sh[s]];
  }
  __syncthreads();
  // PE conv1: h[32][128] bf16 into xn
  for (int i=t; i<32*128; i+=256){
    int s = i >> 7, o = i & 127;
    float h = pe1w[o*3]*gx_sh[s][0] + pe1w[o*3+1]*gx_sh[s][1] + pe1w[o*3+2]*gx_sh[s][2] + pe1b[o];
    h = h*bnsc[o] + bnsh[o];
    xn[s][o] = f2bf(h > 0.f ? h : 0.f);
  }
  __syncthreads();
  // PE conv2 GEMM (K=128): xs += h @ pe2w^T + pe2b
  for (int tt = wid; tt < 32; tt += 4){
    int m0 = (tt & 1)*16, n0 = (tt >> 1)*16;
    f32x4 acc = {0.f,0.f,0.f,0.f};
    #pragma unroll
    for (int kk=0; kk<4; kk++){
      s16x8 a = *(const s16x8*)&xn[m0+c15][kk*32 + g4*8];
      s16x8 bb = *(const s16x8*)&pe2wb[(size_t)(n0+c15)*128 + kk*32 + g4*8];
      acc = mfma16(a, bb, acc);
    }
    int col = n0 + c15;
    float bias = pe2b[col];
    #pragma unroll
    for (int r=0;r<4;r++) xs[m0 + g4*4 + r][col] += acc[r] + bias;
  }
  __syncthreads();

  for (int l=0; l<NL; ++l){
    // ---- LN1 ----
    ln_block(xs, xn, ln1s + l*NC, ln1b + l*NC, t);
    __syncthreads();
    // ---- QKV GEMM (K=256 -> 768 cols) ----
    const u16* Wq = ipwb + (size_t)l*768*NC;
    const float* bq = ipb + l*768;
    for (int tt=wid; tt<96; tt+=4){
      int m0 = (tt & 1)*16, n0 = (tt >> 1)*16;
      f32x4 acc = {0.f,0.f,0.f,0.f};
      #pragma unroll
      for (int kk=0;kk<8;kk++){
        s16x8 a = *(const s16x8*)&xn[m0+c15][kk*32 + g4*8];
        s16x8 bb = *(const s16x8*)&Wq[(size_t)(n0+c15)*NC + kk*32 + g4*8];
        acc = mfma16(a, bb, acc);
      }
      int col = n0 + c15;
      float bias = bq[col];
      #pragma unroll
      for (int r=0;r<4;r++) qb[m0 + g4*4 + r][col] = f2bf(acc[r] + bias);
    }
    __syncthreads();
    // ---- attention: wave = head ----
    {
      const int h = wid;
      f32x4 lac[2][2];
      #pragma unroll
      for (int mt=0;mt<2;mt++)
        #pragma unroll
        for (int nt=0;nt<2;nt++){
          f32x4 acc = {0.f,0.f,0.f,0.f};
          #pragma unroll
          for (int kk=0;kk<2;kk++){
            s16x8 a = *(const s16x8*)&qb[mt*16+c15][h*HDh + kk*32 + g4*8];
            s16x8 bb = *(const s16x8*)&qb[nt*16+c15][256 + h*HDh + kk*32 + g4*8];
            acc = mfma16(a, bb, acc);
          }
          lac[mt][nt] = acc;
        }
      #pragma unroll
      for (int mt=0;mt<2;mt++)
        #pragma unroll
        for (int r=0;r<4;r++){
          float v0 = lac[mt][0][r]*0.125f, v1 = lac[mt][1][r]*0.125f;
          float mx = fmaxf(v0, v1);
          #pragma unroll
          for (int m=1;m<16;m<<=1) mx = fmaxf(mx, __shfl_xor(mx, m));
          float e0 = expf(v0-mx), e1 = expf(v1-mx);
          float sm = e0 + e1;
          #pragma unroll
          for (int m=1;m<16;m<<=1) sm += __shfl_xor(sm, m);
          float inv = 1.f/sm;
          int row = mt*16 + g4*4 + r;
          pb[h][row][c15]      = f2bf(e0*inv);
          pb[h][row][16+c15]   = f2bf(e1*inv);
        }
      // PV (K=32)
      f32x4 oac[2][4];
      #pragma unroll
      for (int nt=0;nt<4;nt++){
        s16x8 bb;
        #pragma unroll
        for (int e=0;e<8;e++) bb[e] = (short)qb[g4*8+e][512 + h*HDh + nt*16 + c15];
        #pragma unroll
        for (int mt=0;mt<2;mt++){
          f32x4 acc = {0.f,0.f,0.f,0.f};
          s16x8 a = *(const s16x8*)&pb[h][mt*16+c15][g4*8];
          acc = mfma16(a, bb, acc);
          oac[mt][nt] = acc;
        }
      }
      __syncthreads();   // qkv fully consumed; xn free for attn-out
      #pragma unroll
      for (int mt=0;mt<2;mt++)
        #pragma unroll
        for (int nt=0;nt<4;nt++)
          #pragma unroll
          for (int r=0;r<4;r++)
            xn[mt*16 + g4*4 + r][h*HDh + nt*16 + c15] = f2bf(oac[mt][nt][r]);
    }
    __syncthreads();
    // ---- out-proj GEMM (K=256), accumulate into xs ----
    const u16* Wo = opwb + (size_t)l*NC*NC;
    const float* bo = opb + l*NC;
    for (int tt=wid; tt<32; tt+=4){
      int m0 = (tt & 1)*16, n0 = (tt >> 1)*16;
      f32x4 acc = {0.f,0.f,0.f,0.f};
      #pragma unroll
      for (int kk=0;kk<8;kk++){
        s16x8 a = *(const s16x8*)&xn[m0+c15][kk*32 + g4*8];
        s16x8 bb = *(const s16x8*)&Wo[(size_t)(n0+c15)*NC + kk*32 + g4*8];
        acc = mfma16(a, bb, acc);
      }
      int col = n0 + c15;
      float bias = bo[col];
      #pragma unroll
      for (int r=0;r<4;r++) xs[m0 + g4*4 + r][col] += acc[r] + bias;
    }
    __syncthreads();
    // ---- LN2 ----
    ln_block(xs, xn, ln2s + l*NC, ln2b + l*NC, t);
    __syncthreads();
    // ---- FF1 (K=256 -> 512 cols, relu) into qb ----
    const u16* W1 = fc1wb + (size_t)l*NDFF*NC;
    for (int tt=wid; tt<64; tt+=4){
      int m0 = (tt & 1)*16, n0 = (tt >> 1)*16;
      f32x4 acc = {0.f,0.f,0.f,0.f};
      #pragma unroll
      for (int kk=0;kk<8;kk++){
        s16x8 a = *(const s16x8*)&xn[m0+c15][kk*32 + g4*8];
        s16x8 bb = *(const s16x8*)&W1[(size_t)(n0+c15)*NC + kk*32 + g4*8];
        acc = mfma16(a, bb, acc);
      }
      int col = n0 + c15;
      float bias = fc1b[l*NDFF + col];
      #pragma unroll
      for (int r=0;r<4;r++){
        float v = acc[r] + bias;
        qb[m0 + g4*4 + r][col] = f2bf(v > 0.f ? v : 0.f);
      }
    }
    __syncthreads();
    // ---- FF2 (K=512), accumulate into xs ----
    const u16* W2 = fc2wb + (size_t)l*NC*NDFF;
    for (int tt=wid; tt<32; tt+=4){
      int m0 = (tt & 1)*16, n0 = (tt >> 1)*16;
      f32x4 acc = {0.f,0.f,0.f,0.f};
      #pragma unroll
      for (int kk=0;kk<16;kk++){
        s16x8 a = *(const s16x8*)&qb[m0+c15][kk*32 + g4*8];
        s16x8 bb = *(const s16x8*)&W2[(size_t)(n0+c15)*NDFF + kk*32 + g4*8];
        acc = mfma16(a, bb, acc);
      }
      int col = n0 + c15;
      float bias = fc2b[l*NC + col];
      #pragma unroll
      for (int r=0;r<4;r++) xs[m0 + g4*4 + r][col] += acc[r] + bias;
    }
    __syncthreads();
  }
  // ---- scatter winners ----
  for (int s=0;s<32;s++){
    int n = idx_sh[s];
    if (firstg[b*NN + n] == p*NSs + s)
      out[((size_t)b*NN + n)*NC + t] = xs[s][t];
  }
}

extern "C" void kernel_launch(void* const* d_in, const int* in_sizes, int n_in,
                              void* d_out, int out_size, void* d_ws, size_t ws_size,
                              hipStream_t stream){
  const float* xyz   = (const float*)d_in[0];
  const float* feat  = (const float*)d_in[1];
  const float* pe1w  = (const float*)d_in[2];
  const float* pe1b  = (const float*)d_in[3];
  const float* bng   = (const float*)d_in[4];
  const float* bnb   = (const float*)d_in[5];
  const float* bnm   = (const float*)d_in[6];
  const float* bnv   = (const float*)d_in[7];
  const float* pe2w  = (const float*)d_in[8];
  const float* pe2b  = (const float*)d_in[9];
  const float* ipw   = (const float*)d_in[10];
  const float* ipb   = (const float*)d_in[11];
  const float* opw   = (const float*)d_in[12];
  const float* opb   = (const float*)d_in[13];
  const float* ln1s  = (const float*)d_in[14];
  const float* ln1b  = (const float*)d_in[15];
  const float* ln2s  = (const float*)d_in[16];
  const float* ln2b  = (const float*)d_in[17];
  const float* fc1w  = (const float*)d_in[18];
  const float* fc1b  = (const float*)d_in[19];
  const float* fc2w  = (const float*)d_in[20];
  const float* fc2b  = (const float*)d_in[21];
  float* out = (float*)d_out;

  char* ws = (char*)d_ws;
  size_t off = 0;
  auto alloc = [&](size_t bytes)->void*{
    void* p = ws + off;
    off = (off + bytes + 255) & ~(size_t)255;
    return p;
  };
  int*   fps_idx = (int*)  alloc((size_t)NB*NPp*4);
  float* newxyz  = (float*)alloc((size_t)NB*NPp*3*4);
  int*   idxg    = (int*)  alloc((size_t)NB*NPp*NSs*4);
  int*   first   = (int*)  alloc((size_t)NB*NN*4);
  float* bnsc    = (float*)alloc(128*4);
  float* bnsh    = (float*)alloc(128*4);
  u16*   ipwb    = (u16*)  alloc((size_t)NL*768*NC*2);
  u16*   opwb    = (u16*)  alloc((size_t)NL*NC*NC*2);
  u16*   fc1wb   = (u16*)  alloc((size_t)NL*NDFF*NC*2);
  u16*   fc2wb   = (u16*)  alloc((size_t)NL*NC*NDFF*2);
  u16*   pe2wb   = (u16*)  alloc((size_t)NC*128*2);
  float* featT   = (float*)(ws + off);
  int useT = (off + (size_t)NB*NN*NC*4 <= ws_size) ? 1 : 0;

  k_prep<<<512, 256, 0, stream>>>(ipw, opw, fc1w, fc2w, pe2w, bng, bnb, bnm, bnv,
                                  ipwb, opwb, fc1wb, fc2wb, pe2wb, bnsc, bnsh, first);
  k_fps<<<NB, 1024, 0, stream>>>(xyz, fps_idx, newxyz);
  k_ballq<<<(NB*NPp)/4, 256, 0, stream>>>(xyz, newxyz, idxg);
  k_first<<<(NB*NPp*NSs)/256, 256, 0, stream>>>(idxg, first);
  k_outinit<<<dim3(NN/32, NB), 256, 0, stream>>>(feat, first, out, featT, useT);
  k_tf<<<NB*NPp, 256, 0, stream>>>(xyz, feat, featT, useT, idxg, newxyz, first,
                                   pe1w, pe1b, bnsc, bnsh, pe2wb, pe2b,
                                   ipwb, ipb, opwb, opb, ln1s, ln1b, ln2s, ln2b,
                                   fc1wb, fc1b, fc2wb, fc2b, out);
  (void)in_sizes; (void)n_in; (void)out_size;
}

// Round 2
// 6652.092 us; speedup vs baseline: 1.1238x; 1.1238x over previous
//
#include <hip/hip_runtime.h>

#define NB 2
#define NN 16384
#define NC 256
#define NPp 2048
#define NSs 32
#define NH 4
#define HDh 64
#define NL 2
#define NDFF 512
#define LFv (NPp*NSs)
#define LNEPS 1e-5f

typedef short s16x8 __attribute__((ext_vector_type(8)));
typedef float f32x4 __attribute__((ext_vector_type(4)));
typedef unsigned short u16;

__device__ __forceinline__ u16 f2bf(float f){
  unsigned u = __float_as_uint(f);
  u += 0x7fffu + ((u>>16)&1u);
  return (u16)(u>>16);
}

__device__ __forceinline__ f32x4 mfma16(s16x8 a, s16x8 b, f32x4 c){
  return __builtin_amdgcn_mfma_f32_16x16x32_bf16(a, b, c, 0, 0, 0);
}

// ---------------- prep: bf16 weights, first[] init, bn fold ----------------
__global__ void k_prep(const float* __restrict__ ipw, const float* __restrict__ opw,
                       const float* __restrict__ fc1w, const float* __restrict__ fc2w,
                       const float* __restrict__ pe2w,
                       const float* __restrict__ bng, const float* __restrict__ bnb,
                       const float* __restrict__ bnm, const float* __restrict__ bnv,
                       u16* ipwb, u16* opwb, u16* fc1wb, u16* fc2wb, u16* pe2wb,
                       float* bnsc, float* bnsh, int* first){
  const int i0 = blockIdx.x*blockDim.x + threadIdx.x;
  const int stride = gridDim.x*blockDim.x;
  for (int i=i0; i<NL*768*NC; i+=stride) ipwb[i] = f2bf(ipw[i]);
  for (int i=i0; i<NL*NC*NC; i+=stride)  opwb[i] = f2bf(opw[i]);
  for (int i=i0; i<NL*NDFF*NC; i+=stride) fc1wb[i] = f2bf(fc1w[i]);
  for (int i=i0; i<NL*NC*NDFF; i+=stride) fc2wb[i] = f2bf(fc2w[i]);
  for (int i=i0; i<NC*128; i+=stride)    pe2wb[i] = f2bf(pe2w[i]);
  for (int i=i0; i<NB*NN; i+=stride)     first[i] = LFv;
  for (int i=i0; i<128; i+=stride){
    float sc = bng[i]*rsqrtf(bnv[i]+LNEPS);
    bnsc[i] = sc; bnsh[i] = bnb[i] - bnm[i]*sc;
  }
}

// ---------------- FPS: one block per batch, 1 barrier per step -------------
__global__ __launch_bounds__(1024,1) void k_fps(const float* __restrict__ xyz,
                                                int* fps_idx, float* newxyz){
#pragma clang fp contract(off)
  const int b = blockIdx.x;
  const int t = threadIdx.x;
  const int lane = t & 63, wid = t >> 6;
  const float* xb = xyz + (size_t)b*NN*3;
  float px[16], py[16], pz[16], dd[16];
  #pragma unroll
  for (int j=0;j<16;j++){
    int i = t + j*1024;
    px[j]=xb[i*3]; py[j]=xb[i*3+1]; pz[j]=xb[i*3+2];
    dd[j]=1e10f;
  }
  __shared__ float wv[2][16];
  __shared__ int   wi[2][16];
  float cx = xb[0], cy = xb[1], cz = xb[2];   // broadcast load of point 0
  if (t==0){
    fps_idx[b*NPp] = 0;
    newxyz[(size_t)b*NPp*3+0]=cx;
    newxyz[(size_t)b*NPp*3+1]=cy;
    newxyz[(size_t)b*NPp*3+2]=cz;
  }
  for (int step=1; step<NPp; ++step){
    // hot loop: min-update + running max (8 VALU/pt)
    float bestv = -1.f;
    #pragma unroll
    for (int j=0;j<16;j++){
      float dx=px[j]-cx, dy=py[j]-cy, dz=pz[j]-cz;
      float d2=(dx*dx+dy*dy)+dz*dz;
      float dn=fminf(dd[j], d2);
      dd[j]=dn;
      bestv=fmaxf(bestv,dn);
    }
    // wave max (value only)
    #pragma unroll
    for (int m=1;m<64;m<<=1) bestv = fmaxf(bestv, __shfl_xor(bestv, m));
    // index scan vs wave max; descending j keeps smallest index on intra-thread tie
    int li = 0x7fffffff;
    #pragma unroll
    for (int j=15;j>=0;j--) if (dd[j]==bestv) li = t + j*1024;
    #pragma unroll
    for (int m=1;m<64;m<<=1){ int o=__shfl_xor(li,m); li = (o<li)?o:li; }
    const int buf = step & 1;
    if (lane==0){ wv[buf][wid]=bestv; wi[buf][wid]=li; }
    __syncthreads();   // the ONLY barrier per step
    // replicated 16-entry reduce (every wave does it; no 2nd barrier needed)
    float v = wv[buf][lane & 15];
    int   i = wi[buf][lane & 15];
    #pragma unroll
    for (int m=1;m<16;m<<=1){
      float ov = __shfl_xor(v, m);
      int   oi = __shfl_xor(i, m);
      bool take = (ov > v) || (ov == v && oi < i);
      v = take ? ov : v;
      i = take ? oi : i;
    }
    // all threads agree on winner i; fetch centroid via cache-broadcast load
    cx = xb[(size_t)i*3]; cy = xb[(size_t)i*3+1]; cz = xb[(size_t)i*3+2];
    if (t==0){
      fps_idx[b*NPp + step] = i;
      newxyz[((size_t)b*NPp+step)*3+0]=cx;
      newxyz[((size_t)b*NPp+step)*3+1]=cy;
      newxyz[((size_t)b*NPp+step)*3+2]=cz;
    }
  }
}

// ---------------- ball query: one wave per center ---------------------------
__global__ __launch_bounds__(256) void k_ballq(const float* __restrict__ xyz,
                                               const float* __restrict__ newxyz,
                                               int* __restrict__ idxg){
#pragma clang fp contract(off)
  const int gw = (blockIdx.x*256 + threadIdx.x) >> 6;
  const int lane = threadIdx.x & 63;
  if (gw >= NB*NPp) return;
  const int b = gw / NPp;
  const float cx=newxyz[(size_t)gw*3], cy=newxyz[(size_t)gw*3+1], cz=newxyz[(size_t)gw*3+2];
  const float* xb = xyz + (size_t)b*NN*3;
  int* op = idxg + (size_t)gw*NSs;
  int count = 0;
  int first_i = 0;
  for (int base=0; base<NN; base+=64){
    const int i = base + lane;
    float dx=xb[i*3]-cx, dy=xb[i*3+1]-cy, dz=xb[i*3+2]-cz;
    float d2=(dx*dx+dy*dy)+dz*dz;
    bool hit = d2 < 1.0f;
    unsigned long long m = __ballot(hit);
    if (m){
      int rank = __popcll(m & ((1ull<<lane)-1ull));
      int slot = count + rank;
      if (hit && slot < NSs) op[slot] = i;
      if (count == 0) first_i = base + (__ffsll((unsigned long long)m)-1);
      count += __popcll(m);
      if (count >= NSs) break;
    }
  }
  if (count < NSs){
    if (lane >= count && lane < NSs) op[lane] = (count>0) ? first_i : 0;
  }
}

// ---------------- first-occurrence (segment_min of flat pos) ---------------
__global__ void k_first(const int* __restrict__ idxg, int* __restrict__ first){
  int i = blockIdx.x*blockDim.x + threadIdx.x;
  if (i < NB*NPp*NSs){
    int b = i / (NPp*NSs);
    int pos = i % (NPp*NSs);
    atomicMin(&first[b*NN + idxg[i]], pos);
  }
}

// ---------------- transpose features -> out (non-winners) + featT ----------
__global__ __launch_bounds__(256) void k_outinit(const float* __restrict__ feat,
                                                 const int* __restrict__ first,
                                                 float* __restrict__ out,
                                                 float* __restrict__ featT, int useT){
  __shared__ float T[32][33];
  const int b = blockIdx.y;
  const int n0 = blockIdx.x*32;
  const int t = threadIdx.x;
  const int tn = t & 31, tc = t >> 5;          // tc in 0..7
  for (int cb=0; cb<NC; cb+=32){
    #pragma unroll
    for (int i=0;i<32;i+=8)
      T[tc+i][tn] = feat[((size_t)b*NC + cb+tc+i)*NN + n0+tn];
    __syncthreads();
    #pragma unroll
    for (int i=0;i<32;i+=8){
      int n = n0 + tc + i;
      float v = T[tn][tc+i];
      if (useT) featT[((size_t)b*NN + n)*NC + cb+tn] = v;
      if (first[b*NN+n] == LFv) out[((size_t)b*NN + n)*NC + cb+tn] = v;
    }
    __syncthreads();
  }
}

// ---------------- fused group + PE + 2-layer transformer + scatter ---------
__device__ __forceinline__ void ln_block(float (*xs)[NC], u16 (*xn)[264],
                                         const float* __restrict__ s_,
                                         const float* __restrict__ b_, int t){
  const int s = t >> 3, j = t & 7;            // 8 threads per row
  float v[32];
  float sum = 0.f;
  #pragma unroll
  for (int k=0;k<32;k++){ v[k]=xs[s][j*32+k]; sum += v[k]; }
  #pragma unroll
  for (int m=1;m<8;m<<=1) sum += __shfl_xor(sum, m);
  const float mean = sum * (1.f/256.f);
  float vs = 0.f;
  #pragma unroll
  for (int k=0;k<32;k++){ float d=v[k]-mean; vs += d*d; }
  #pragma unroll
  for (int m=1;m<8;m<<=1) vs += __shfl_xor(vs, m);
  const float rstd = rsqrtf(vs*(1.f/256.f) + LNEPS);
  #pragma unroll
  for (int k=0;k<32;k++){
    int c = j*32+k;
    float y = (v[k]-mean)*rstd*s_[c] + b_[c];
    xs[s][c] = y;
    xn[s][c] = f2bf(y);
  }
}

__global__ __launch_bounds__(256,1) void k_tf(
    const float* __restrict__ xyz, const float* __restrict__ features,
    const float* __restrict__ featT, int useT,
    const int* __restrict__ idxg, const float* __restrict__ newxyz,
    const int* __restrict__ firstg,
    const float* __restrict__ pe1w, const float* __restrict__ pe1b,
    const float* __restrict__ bnsc, const float* __restrict__ bnsh,
    const u16* __restrict__ pe2wb, const float* __restrict__ pe2b,
    const u16* __restrict__ ipwb, const float* __restrict__ ipb,
    const u16* __restrict__ opwb, const float* __restrict__ opb,
    const float* __restrict__ ln1s, const float* __restrict__ ln1b,
    const float* __restrict__ ln2s, const float* __restrict__ ln2b,
    const u16* __restrict__ fc1wb, const float* __restrict__ fc1b,
    const u16* __restrict__ fc2wb, const float* __restrict__ fc2b,
    float* __restrict__ out){
  __shared__ float xs[32][NC];        // residual stream (fp32)
  __shared__ u16  xn[32][264];        // LN output / attn-out (bf16, A operand)
  __shared__ u16  qb[32][776];        // qkv (bf16), reused as FF hidden
  __shared__ u16  pb[NH][32][40];     // softmax P per head
  __shared__ int  idx_sh[32];
  __shared__ float gx_sh[32][3];

  const int seq = blockIdx.x;
  const int b = seq / NPp, p = seq % NPp;
  const int t = threadIdx.x, lane = t & 63, wid = t >> 6;
  const int c15 = lane & 15, g4 = lane >> 4;

  if (t < 32) idx_sh[t] = idxg[(size_t)seq*NSs + t];
  __syncthreads();
  if (t < 96){
    int s = t/3, d = t%3;
    gx_sh[s][d] = xyz[((size_t)b*NN + idx_sh[s])*3 + d] - newxyz[(size_t)seq*3 + d];
  }
  if (useT){
    for (int s=0;s<32;s++) xs[s][t] = featT[((size_t)b*NN + idx_sh[s])*NC + t];
  } else {
    for (int s=0;s<32;s++) xs[s][t] = features[((size_t)b*NC + t)*NN + idx_sh[s]];
  }
  __syncthreads();
  // PE conv1: h[32][128] bf16 into xn
  for (int i=t; i<32*128; i+=256){
    int s = i >> 7, o = i & 127;
    float h = pe1w[o*3]*gx_sh[s][0] + pe1w[o*3+1]*gx_sh[s][1] + pe1w[o*3+2]*gx_sh[s][2] + pe1b[o];
    h = h*bnsc[o] + bnsh[o];
    xn[s][o] = f2bf(h > 0.f ? h : 0.f);
  }
  __syncthreads();
  // PE conv2 GEMM (K=128): xs += h @ pe2w^T + pe2b
  for (int tt = wid; tt < 32; tt += 4){
    int m0 = (tt & 1)*16, n0 = (tt >> 1)*16;
    f32x4 acc = {0.f,0.f,0.f,0.f};
    #pragma unroll
    for (int kk=0; kk<4; kk++){
      s16x8 a = *(const s16x8*)&xn[m0+c15][kk*32 + g4*8];
      s16x8 bb = *(const s16x8*)&pe2wb[(size_t)(n0+c15)*128 + kk*32 + g4*8];
      acc = mfma16(a, bb, acc);
    }
    int col = n0 + c15;
    float bias = pe2b[col];
    #pragma unroll
    for (int r=0;r<4;r++) xs[m0 + g4*4 + r][col] += acc[r] + bias;
  }
  __syncthreads();

  for (int l=0; l<NL; ++l){
    // ---- LN1 ----
    ln_block(xs, xn, ln1s + l*NC, ln1b + l*NC, t);
    __syncthreads();
    // ---- QKV GEMM (K=256 -> 768 cols) ----
    const u16* Wq = ipwb + (size_t)l*768*NC;
    const float* bq = ipb + l*768;
    for (int tt=wid; tt<96; tt+=4){
      int m0 = (tt & 1)*16, n0 = (tt >> 1)*16;
      f32x4 acc = {0.f,0.f,0.f,0.f};
      #pragma unroll
      for (int kk=0;kk<8;kk++){
        s16x8 a = *(const s16x8*)&xn[m0+c15][kk*32 + g4*8];
        s16x8 bb = *(const s16x8*)&Wq[(size_t)(n0+c15)*NC + kk*32 + g4*8];
        acc = mfma16(a, bb, acc);
      }
      int col = n0 + c15;
      float bias = bq[col];
      #pragma unroll
      for (int r=0;r<4;r++) qb[m0 + g4*4 + r][col] = f2bf(acc[r] + bias);
    }
    __syncthreads();
    // ---- attention: wave = head ----
    {
      const int h = wid;
      f32x4 lac[2][2];
      #pragma unroll
      for (int mt=0;mt<2;mt++)
        #pragma unroll
        for (int nt=0;nt<2;nt++){
          f32x4 acc = {0.f,0.f,0.f,0.f};
          #pragma unroll
          for (int kk=0;kk<2;kk++){
            s16x8 a = *(const s16x8*)&qb[mt*16+c15][h*HDh + kk*32 + g4*8];
            s16x8 bb = *(const s16x8*)&qb[nt*16+c15][256 + h*HDh + kk*32 + g4*8];
            acc = mfma16(a, bb, acc);
          }
          lac[mt][nt] = acc;
        }
      #pragma unroll
      for (int mt=0;mt<2;mt++)
        #pragma unroll
        for (int r=0;r<4;r++){
          float v0 = lac[mt][0][r]*0.125f, v1 = lac[mt][1][r]*0.125f;
          float mx = fmaxf(v0, v1);
          #pragma unroll
          for (int m=1;m<16;m<<=1) mx = fmaxf(mx, __shfl_xor(mx, m));
          float e0 = expf(v0-mx), e1 = expf(v1-mx);
          float sm = e0 + e1;
          #pragma unroll
          for (int m=1;m<16;m<<=1) sm += __shfl_xor(sm, m);
          float inv = 1.f/sm;
          int row = mt*16 + g4*4 + r;
          pb[h][row][c15]      = f2bf(e0*inv);
          pb[h][row][16+c15]   = f2bf(e1*inv);
        }
      // PV (K=32)
      f32x4 oac[2][4];
      #pragma unroll
      for (int nt=0;nt<4;nt++){
        s16x8 bb;
        #pragma unroll
        for (int e=0;e<8;e++) bb[e] = (short)qb[g4*8+e][512 + h*HDh + nt*16 + c15];
        #pragma unroll
        for (int mt=0;mt<2;mt++){
          f32x4 acc = {0.f,0.f,0.f,0.f};
          s16x8 a = *(const s16x8*)&pb[h][mt*16+c15][g4*8];
          acc = mfma16(a, bb, acc);
          oac[mt][nt] = acc;
        }
      }
      __syncthreads();   // qkv fully consumed; xn free for attn-out
      #pragma unroll
      for (int mt=0;mt<2;mt++)
        #pragma unroll
        for (int nt=0;nt<4;nt++)
          #pragma unroll
          for (int r=0;r<4;r++)
            xn[mt*16 + g4*4 + r][h*HDh + nt*16 + c15] = f2bf(oac[mt][nt][r]);
    }
    __syncthreads();
    // ---- out-proj GEMM (K=256), accumulate into xs ----
    const u16* Wo = opwb + (size_t)l*NC*NC;
    const float* bo = opb + l*NC;
    for (int tt=wid; tt<32; tt+=4){
      int m0 = (tt & 1)*16, n0 = (tt >> 1)*16;
      f32x4 acc = {0.f,0.f,0.f,0.f};
      #pragma unroll
      for (int kk=0;kk<8;kk++){
        s16x8 a = *(const s16x8*)&xn[m0+c15][kk*32 + g4*8];
        s16x8 bb = *(const s16x8*)&Wo[(size_t)(n0+c15)*NC + kk*32 + g4*8];
        acc = mfma16(a, bb, acc);
      }
      int col = n0 + c15;
      float bias = bo[col];
      #pragma unroll
      for (int r=0;r<4;r++) xs[m0 + g4*4 + r][col] += acc[r] + bias;
    }
    __syncthreads();
    // ---- LN2 ----
    ln_block(xs, xn, ln2s + l*NC, ln2b + l*NC, t);
    __syncthreads();
    // ---- FF1 (K=256 -> 512 cols, relu) into qb ----
    const u16* W1 = fc1wb + (size_t)l*NDFF*NC;
    for (int tt=wid; tt<64; tt+=4){
      int m0 = (tt & 1)*16, n0 = (tt >> 1)*16;
      f32x4 acc = {0.f,0.f,0.f,0.f};
      #pragma unroll
      for (int kk=0;kk<8;kk++){
        s16x8 a = *(const s16x8*)&xn[m0+c15][kk*32 + g4*8];
        s16x8 bb = *(const s16x8*)&W1[(size_t)(n0+c15)*NC + kk*32 + g4*8];
        acc = mfma16(a, bb, acc);
      }
      int col = n0 + c15;
      float bias = fc1b[l*NDFF + col];
      #pragma unroll
      for (int r=0;r<4;r++){
        float v = acc[r] + bias;
        qb[m0 + g4*4 + r][col] = f2bf(v > 0.f ? v : 0.f);
      }
    }
    __syncthreads();
    // ---- FF2 (K=512), accumulate into xs ----
    const u16* W2 = fc2wb + (size_t)l*NC*NDFF;
    for (int tt=wid; tt<32; tt+=4){
      int m0 = (tt & 1)*16, n0 = (tt >> 1)*16;
      f32x4 acc = {0.f,0.f,0.f,0.f};
      #pragma unroll
      for (int kk=0;kk<16;kk++){
        s16x8 a = *(const s16x8*)&qb[m0+c15][kk*32 + g4*8];
        s16x8 bb = *(const s16x8*)&W2[(size_t)(n0+c15)*NDFF + kk*32 + g4*8];
        acc = mfma16(a, bb, acc);
      }
      int col = n0 + c15;
      float bias = fc2b[l*NC + col];
      #pragma unroll
      for (int r=0;r<4;r++) xs[m0 + g4*4 + r][col] += acc[r] + bias;
    }
    __syncthreads();
  }
  // ---- scatter winners ----
  for (int s=0;s<32;s++){
    int n = idx_sh[s];
    if (firstg[b*NN + n] == p*NSs + s)
      out[((size_t)b*NN + n)*NC + t] = xs[s][t];
  }
}

extern "C" void kernel_launch(void* const* d_in, const int* in_sizes, int n_in,
                              void* d_out, int out_size, void* d_ws, size_t ws_size,
                              hipStream_t stream){
  const float* xyz   = (const float*)d_in[0];
  const float* feat  = (const float*)d_in[1];
  const float* pe1w  = (const float*)d_in[2];
  const float* pe1b  = (const float*)d_in[3];
  const float* bng   = (const float*)d_in[4];
  const float* bnb   = (const float*)d_in[5];
  const float* bnm   = (const float*)d_in[6];
  const float* bnv   = (const float*)d_in[7];
  const float* pe2w  = (const float*)d_in[8];
  const float* pe2b  = (const float*)d_in[9];
  const float* ipw   = (const float*)d_in[10];
  const float* ipb   = (const float*)d_in[11];
  const float* opw   = (const float*)d_in[12];
  const float* opb   = (const float*)d_in[13];
  const float* ln1s  = (const float*)d_in[14];
  const float* ln1b  = (const float*)d_in[15];
  const float* ln2s  = (const float*)d_in[16];
  const float* ln2b  = (const float*)d_in[17];
  const float* fc1w  = (const float*)d_in[18];
  const float* fc1b  = (const float*)d_in[19];
  const float* fc2w  = (const float*)d_in[20];
  const float* fc2b  = (const float*)d_in[21];
  float* out = (float*)d_out;

  char* ws = (char*)d_ws;
  size_t off = 0;
  auto alloc = [&](size_t bytes)->void*{
    void* p = ws + off;
    off = (off + bytes + 255) & ~(size_t)255;
    return p;
  };
  int*   fps_idx = (int*)  alloc((size_t)NB*NPp*4);
  float* newxyz  = (float*)alloc((size_t)NB*NPp*3*4);
  int*   idxg    = (int*)  alloc((size_t)NB*NPp*NSs*4);
  int*   first   = (int*)  alloc((size_t)NB*NN*4);
  float* bnsc    = (float*)alloc(128*4);
  float* bnsh    = (float*)alloc(128*4);
  u16*   ipwb    = (u16*)  alloc((size_t)NL*768*NC*2);
  u16*   opwb    = (u16*)  alloc((size_t)NL*NC*NC*2);
  u16*   fc1wb   = (u16*)  alloc((size_t)NL*NDFF*NC*2);
  u16*   fc2wb   = (u16*)  alloc((size_t)NL*NC*NDFF*2);
  u16*   pe2wb   = (u16*)  alloc((size_t)NC*128*2);
  float* featT   = (float*)(ws + off);
  int useT = (off + (size_t)NB*NN*NC*4 <= ws_size) ? 1 : 0;

  k_prep<<<512, 256, 0, stream>>>(ipw, opw, fc1w, fc2w, pe2w, bng, bnb, bnm, bnv,
                                  ipwb, opwb, fc1wb, fc2wb, pe2wb, bnsc, bnsh, first);
  k_fps<<<NB, 1024, 0, stream>>>(xyz, fps_idx, newxyz);
  k_ballq<<<(NB*NPp)/4, 256, 0, stream>>>(xyz, newxyz, idxg);
  k_first<<<(NB*NPp*NSs)/256, 256, 0, stream>>>(idxg, first);
  k_outinit<<<dim3(NN/32, NB), 256, 0, stream>>>(feat, first, out, featT, useT);
  k_tf<<<NB*NPp, 256, 0, stream>>>(xyz, feat, featT, useT, idxg, newxyz, first,
                                   pe1w, pe1b, bnsc, bnsh, pe2wb, pe2b,
                                   ipwb, ipb, opwb, opb, ln1s, ln1b, ln2s, ln2b,
                                   fc1wb, fc1b, fc2wb, fc2b, out);
  (void)in_sizes; (void)n_in; (void)out_size;
}

// Round 3
// 6449.018 us; speedup vs baseline: 1.1592x; 1.0315x over previous
//
#include <hip/hip_runtime.h>

#define NB 2
#define NN 16384
#define NC 256
#define NPp 2048
#define NSs 32
#define NH 4
#define HDh 64
#define NL 2
#define NDFF 512
#define LFv (NPp*NSs)
#define LNEPS 1e-5f

typedef short s16x8 __attribute__((ext_vector_type(8)));
typedef float f32x4 __attribute__((ext_vector_type(4)));
typedef float f32x2 __attribute__((ext_vector_type(2)));
typedef unsigned short u16;

__device__ __forceinline__ u16 f2bf(float f){
  unsigned u = __float_as_uint(f);
  u += 0x7fffu + ((u>>16)&1u);
  return (u16)(u>>16);
}

__device__ __forceinline__ f32x4 mfma16(s16x8 a, s16x8 b, f32x4 c){
  return __builtin_amdgcn_mfma_f32_16x16x32_bf16(a, b, c, 0, 0, 0);
}

// packed f32 ops (component-wise IEEE identical to scalar; no fma fusion)
__device__ __forceinline__ f32x2 pk_add(f32x2 a, f32x2 b){
  f32x2 d; asm("v_pk_add_f32 %0, %1, %2" : "=v"(d) : "v"(a), "v"(b)); return d;
}
__device__ __forceinline__ f32x2 pk_mul(f32x2 a, f32x2 b){
  f32x2 d; asm("v_pk_mul_f32 %0, %1, %2" : "=v"(d) : "v"(a), "v"(b)); return d;
}

// ---------------- prep: bf16 weights, first[] init, bn fold ----------------
__global__ void k_prep(const float* __restrict__ ipw, const float* __restrict__ opw,
                       const float* __restrict__ fc1w, const float* __restrict__ fc2w,
                       const float* __restrict__ pe2w,
                       const float* __restrict__ bng, const float* __restrict__ bnb,
                       const float* __restrict__ bnm, const float* __restrict__ bnv,
                       u16* ipwb, u16* opwb, u16* fc1wb, u16* fc2wb, u16* pe2wb,
                       float* bnsc, float* bnsh, int* first){
  const int i0 = blockIdx.x*blockDim.x + threadIdx.x;
  const int stride = gridDim.x*blockDim.x;
  for (int i=i0; i<NL*768*NC; i+=stride) ipwb[i] = f2bf(ipw[i]);
  for (int i=i0; i<NL*NC*NC; i+=stride)  opwb[i] = f2bf(opw[i]);
  for (int i=i0; i<NL*NDFF*NC; i+=stride) fc1wb[i] = f2bf(fc1w[i]);
  for (int i=i0; i<NL*NC*NDFF; i+=stride) fc2wb[i] = f2bf(fc2w[i]);
  for (int i=i0; i<NC*128; i+=stride)    pe2wb[i] = f2bf(pe2w[i]);
  for (int i=i0; i<NB*NN; i+=stride)     first[i] = LFv;
  for (int i=i0; i<128; i+=stride){
    float sc = bng[i]*rsqrtf(bnv[i]+LNEPS);
    bnsc[i] = sc; bnsh[i] = bnb[i] - bnm[i]*sc;
  }
}

// ---------------- FPS: one block per batch, 1 barrier per step -------------
__global__ __launch_bounds__(1024,1) void k_fps(const float* __restrict__ xyz,
                                                int* fps_idx, float* newxyz){
#pragma clang fp contract(off)
  const int b = blockIdx.x;
  const int t = threadIdx.x;
  const float* xb = xyz + (size_t)b*NN*3;
  // pair layout: pair m holds points t+(2m)*1024 (.x) and t+(2m+1)*1024 (.y)
  f32x2 px2[8], py2[8], pz2[8], dd2[8];
  #pragma unroll
  for (int m=0;m<8;m++){
    int i0 = t + (2*m)*1024, i1 = t + (2*m+1)*1024;
    px2[m] = f32x2{xb[i0*3],   xb[i1*3]};
    py2[m] = f32x2{xb[i0*3+1], xb[i1*3+1]};
    pz2[m] = f32x2{xb[i0*3+2], xb[i1*3+2]};
    dd2[m] = f32x2{1e10f, 1e10f};
  }
  __shared__ unsigned long long keybuf[4];
  if (t < 4) keybuf[t] = 0ull;
  float wx = xb[0], wy = xb[1], wz = xb[2];
  if (t==0){
    fps_idx[b*NPp] = 0;
    newxyz[(size_t)b*NPp*3+0]=wx;
    newxyz[(size_t)b*NPp*3+1]=wy;
    newxyz[(size_t)b*NPp*3+2]=wz;
  }
  float ncx = -wx, ncy = -wy, ncz = -wz;
  __syncthreads();
  for (int step=1; step<NPp; ++step){
    const f32x2 ncx2 = {ncx,ncx}, ncy2 = {ncy,ncy}, ncz2 = {ncz,ncz};
    // hot loop: exact ((dx*dx+dy*dy)+dz*dz), packed 2 pts/instr
    #pragma unroll
    for (int m=0;m<8;m++){
      f32x2 dx = pk_add(px2[m], ncx2);
      f32x2 dy = pk_add(py2[m], ncy2);
      f32x2 dz = pk_add(pz2[m], ncz2);
      f32x2 s  = pk_add(pk_add(pk_mul(dx,dx), pk_mul(dy,dy)), pk_mul(dz,dz));
      f32x2 d  = dd2[m];
      d.x = fminf(d.x, s.x);
      d.y = fminf(d.y, s.y);
      dd2[m] = d;
    }
    // per-thread max via max3 tree (fmax is exact -> reassociation safe)
    float t0 = fmaxf(fmaxf(dd2[0].x, dd2[0].y), dd2[1].x);
    float t1 = fmaxf(fmaxf(dd2[1].y, dd2[2].x), dd2[2].y);
    float t2 = fmaxf(fmaxf(dd2[3].x, dd2[3].y), dd2[4].x);
    float t3 = fmaxf(fmaxf(dd2[4].y, dd2[5].x), dd2[5].y);
    float t4 = fmaxf(fmaxf(dd2[6].x, dd2[6].y), dd2[7].x);
    float m0 = fmaxf(fmaxf(t0, t1), t2);
    float m1 = fmaxf(fmaxf(t3, t4), dd2[7].y);
    float M  = fmaxf(m0, m1);
    // wave max
    #pragma unroll
    for (int m=1;m<64;m<<=1) M = fmaxf(M, __shfl_xor(M, m));
    // per-thread smallest own index equal to wave max (descending scan)
    int li = 0x7fffffff;
    #pragma unroll
    for (int m=7;m>=0;m--){
      if (dd2[m].y == M) li = t + (2*m+1)*1024;
      if (dd2[m].x == M) li = t + (2*m)*1024;
    }
    const int buf = step & 3;
    if (li != 0x7fffffff){
      unsigned long long k = ((unsigned long long)__float_as_uint(M) << 32)
                           | (unsigned)(0x7fffffff - li);
      atomicMax(&keybuf[buf], k);
    }
    __syncthreads();   // the ONLY barrier per step
    const unsigned long long kk = keybuf[buf];
    const int widx = 0x7fffffff - (int)(unsigned)(kk & 0xffffffffu);
    const int iu = __builtin_amdgcn_readfirstlane(widx);
    const float* cp = xb + (size_t)iu*3;     // scalar (uniform) load path
    wx = cp[0]; wy = cp[1]; wz = cp[2];
    ncx = -wx; ncy = -wy; ncz = -wz;
    if (t==0){
      fps_idx[b*NPp + step] = iu;
      newxyz[((size_t)b*NPp+step)*3+0]=wx;
      newxyz[((size_t)b*NPp+step)*3+1]=wy;
      newxyz[((size_t)b*NPp+step)*3+2]=wz;
      keybuf[(step+2) & 3] = 0ull;   // reset at distance 2 (race-free, see analysis)
    }
  }
}

// ---------------- ball query: one wave per center ---------------------------
__global__ __launch_bounds__(256) void k_ballq(const float* __restrict__ xyz,
                                               const float* __restrict__ newxyz,
                                               int* __restrict__ idxg){
#pragma clang fp contract(off)
  const int gw = (blockIdx.x*256 + threadIdx.x) >> 6;
  const int lane = threadIdx.x & 63;
  if (gw >= NB*NPp) return;
  const int b = gw / NPp;
  const float cx=newxyz[(size_t)gw*3], cy=newxyz[(size_t)gw*3+1], cz=newxyz[(size_t)gw*3+2];
  const float* xb = xyz + (size_t)b*NN*3;
  int* op = idxg + (size_t)gw*NSs;
  int count = 0;
  int first_i = 0;
  for (int base=0; base<NN; base+=64){
    const int i = base + lane;
    float dx=xb[i*3]-cx, dy=xb[i*3+1]-cy, dz=xb[i*3+2]-cz;
    float d2=(dx*dx+dy*dy)+dz*dz;
    bool hit = d2 < 1.0f;
    unsigned long long m = __ballot(hit);
    if (m){
      int rank = __popcll(m & ((1ull<<lane)-1ull));
      int slot = count + rank;
      if (hit && slot < NSs) op[slot] = i;
      if (count == 0) first_i = base + (__ffsll((unsigned long long)m)-1);
      count += __popcll(m);
      if (count >= NSs) break;
    }
  }
  if (count < NSs){
    if (lane >= count && lane < NSs) op[lane] = (count>0) ? first_i : 0;
  }
}

// ---------------- first-occurrence (segment_min of flat pos) ---------------
__global__ void k_first(const int* __restrict__ idxg, int* __restrict__ first){
  int i = blockIdx.x*blockDim.x + threadIdx.x;
  if (i < NB*NPp*NSs){
    int b = i / (NPp*NSs);
    int pos = i % (NPp*NSs);
    atomicMin(&first[b*NN + idxg[i]], pos);
  }
}

// ---------------- transpose features -> out (non-winners) + featT ----------
__global__ __launch_bounds__(256) void k_outinit(const float* __restrict__ feat,
                                                 const int* __restrict__ first,
                                                 float* __restrict__ out,
                                                 float* __restrict__ featT, int useT){
  __shared__ float T[32][33];
  const int b = blockIdx.y;
  const int n0 = blockIdx.x*32;
  const int t = threadIdx.x;
  const int tn = t & 31, tc = t >> 5;          // tc in 0..7
  for (int cb=0; cb<NC; cb+=32){
    #pragma unroll
    for (int i=0;i<32;i+=8)
      T[tc+i][tn] = feat[((size_t)b*NC + cb+tc+i)*NN + n0+tn];
    __syncthreads();
    #pragma unroll
    for (int i=0;i<32;i+=8){
      int n = n0 + tc + i;
      float v = T[tn][tc+i];
      if (useT) featT[((size_t)b*NN + n)*NC + cb+tn] = v;
      if (first[b*NN+n] == LFv) out[((size_t)b*NN + n)*NC + cb+tn] = v;
    }
    __syncthreads();
  }
}

// ---------------- fused group + PE + 2-layer transformer + scatter ---------
__device__ __forceinline__ void ln_block(float (*xs)[NC], u16 (*xn)[264],
                                         const float* __restrict__ s_,
                                         const float* __restrict__ b_, int t){
  const int s = t >> 3, j = t & 7;            // 8 threads per row
  float v[32];
  float sum = 0.f;
  #pragma unroll
  for (int k=0;k<32;k++){ v[k]=xs[s][j*32+k]; sum += v[k]; }
  #pragma unroll
  for (int m=1;m<8;m<<=1) sum += __shfl_xor(sum, m);
  const float mean = sum * (1.f/256.f);
  float vs = 0.f;
  #pragma unroll
  for (int k=0;k<32;k++){ float d=v[k]-mean; vs += d*d; }
  #pragma unroll
  for (int m=1;m<8;m<<=1) vs += __shfl_xor(vs, m);
  const float rstd = rsqrtf(vs*(1.f/256.f) + LNEPS);
  #pragma unroll
  for (int k=0;k<32;k++){
    int c = j*32+k;
    float y = (v[k]-mean)*rstd*s_[c] + b_[c];
    xs[s][c] = y;
    xn[s][c] = f2bf(y);
  }
}

__global__ __launch_bounds__(256,1) void k_tf(
    const float* __restrict__ xyz, const float* __restrict__ features,
    const float* __restrict__ featT, int useT,
    const int* __restrict__ idxg, const float* __restrict__ newxyz,
    const int* __restrict__ firstg,
    const float* __restrict__ pe1w, const float* __restrict__ pe1b,
    const float* __restrict__ bnsc, const float* __restrict__ bnsh,
    const u16* __restrict__ pe2wb, const float* __restrict__ pe2b,
    const u16* __restrict__ ipwb, const float* __restrict__ ipb,
    const u16* __restrict__ opwb, const float* __restrict__ opb,
    const float* __restrict__ ln1s, const float* __restrict__ ln1b,
    const float* __restrict__ ln2s, const float* __restrict__ ln2b,
    const u16* __restrict__ fc1wb, const float* __restrict__ fc1b,
    const u16* __restrict__ fc2wb, const float* __restrict__ fc2b,
    float* __restrict__ out){
  __shared__ float xs[32][NC];        // residual stream (fp32)
  __shared__ u16  xn[32][264];        // LN output / attn-out (bf16, A operand)
  __shared__ u16  qb[32][776];        // qkv (bf16), reused as FF hidden
  __shared__ u16  pb[NH][32][40];     // softmax P per head
  __shared__ int  idx_sh[32];
  __shared__ float gx_sh[32][3];

  const int seq = blockIdx.x;
  const int b = seq / NPp, p = seq % NPp;
  const int t = threadIdx.x, lane = t & 63, wid = t >> 6;
  const int c15 = lane & 15, g4 = lane >> 4;

  if (t < 32) idx_sh[t] = idxg[(size_t)seq*NSs + t];
  __syncthreads();
  if (t < 96){
    int s = t/3, d = t%3;
    gx_sh[s][d] = xyz[((size_t)b*NN + idx_sh[s])*3 + d] - newxyz[(size_t)seq*3 + d];
  }
  if (useT){
    for (int s=0;s<32;s++) xs[s][t] = featT[((size_t)b*NN + idx_sh[s])*NC + t];
  } else {
    for (int s=0;s<32;s++) xs[s][t] = features[((size_t)b*NC + t)*NN + idx_sh[s]];
  }
  __syncthreads();
  // PE conv1: h[32][128] bf16 into xn
  for (int i=t; i<32*128; i+=256){
    int s = i >> 7, o = i & 127;
    float h = pe1w[o*3]*gx_sh[s][0] + pe1w[o*3+1]*gx_sh[s][1] + pe1w[o*3+2]*gx_sh[s][2] + pe1b[o];
    h = h*bnsc[o] + bnsh[o];
    xn[s][o] = f2bf(h > 0.f ? h : 0.f);
  }
  __syncthreads();
  // PE conv2 GEMM (K=128): xs += h @ pe2w^T + pe2b
  for (int tt = wid; tt < 32; tt += 4){
    int m0 = (tt & 1)*16, n0 = (tt >> 1)*16;
    f32x4 acc = {0.f,0.f,0.f,0.f};
    #pragma unroll
    for (int kk=0; kk<4; kk++){
      s16x8 a = *(const s16x8*)&xn[m0+c15][kk*32 + g4*8];
      s16x8 bb = *(const s16x8*)&pe2wb[(size_t)(n0+c15)*128 + kk*32 + g4*8];
      acc = mfma16(a, bb, acc);
    }
    int col = n0 + c15;
    float bias = pe2b[col];
    #pragma unroll
    for (int r=0;r<4;r++) xs[m0 + g4*4 + r][col] += acc[r] + bias;
  }
  __syncthreads();

  for (int l=0; l<NL; ++l){
    // ---- LN1 ----
    ln_block(xs, xn, ln1s + l*NC, ln1b + l*NC, t);
    __syncthreads();
    // ---- QKV GEMM (K=256 -> 768 cols) ----
    const u16* Wq = ipwb + (size_t)l*768*NC;
    const float* bq = ipb + l*768;
    for (int tt=wid; tt<96; tt+=4){
      int m0 = (tt & 1)*16, n0 = (tt >> 1)*16;
      f32x4 acc = {0.f,0.f,0.f,0.f};
      #pragma unroll
      for (int kk=0;kk<8;kk++){
        s16x8 a = *(const s16x8*)&xn[m0+c15][kk*32 + g4*8];
        s16x8 bb = *(const s16x8*)&Wq[(size_t)(n0+c15)*NC + kk*32 + g4*8];
        acc = mfma16(a, bb, acc);
      }
      int col = n0 + c15;
      float bias = bq[col];
      #pragma unroll
      for (int r=0;r<4;r++) qb[m0 + g4*4 + r][col] = f2bf(acc[r] + bias);
    }
    __syncthreads();
    // ---- attention: wave = head ----
    {
      const int h = wid;
      f32x4 lac[2][2];
      #pragma unroll
      for (int mt=0;mt<2;mt++)
        #pragma unroll
        for (int nt=0;nt<2;nt++){
          f32x4 acc = {0.f,0.f,0.f,0.f};
          #pragma unroll
          for (int kk=0;kk<2;kk++){
            s16x8 a = *(const s16x8*)&qb[mt*16+c15][h*HDh + kk*32 + g4*8];
            s16x8 bb = *(const s16x8*)&qb[nt*16+c15][256 + h*HDh + kk*32 + g4*8];
            acc = mfma16(a, bb, acc);
          }
          lac[mt][nt] = acc;
        }
      #pragma unroll
      for (int mt=0;mt<2;mt++)
        #pragma unroll
        for (int r=0;r<4;r++){
          float v0 = lac[mt][0][r]*0.125f, v1 = lac[mt][1][r]*0.125f;
          float mx = fmaxf(v0, v1);
          #pragma unroll
          for (int m=1;m<16;m<<=1) mx = fmaxf(mx, __shfl_xor(mx, m));
          float e0 = expf(v0-mx), e1 = expf(v1-mx);
          float sm = e0 + e1;
          #pragma unroll
          for (int m=1;m<16;m<<=1) sm += __shfl_xor(sm, m);
          float inv = 1.f/sm;
          int row = mt*16 + g4*4 + r;
          pb[h][row][c15]      = f2bf(e0*inv);
          pb[h][row][16+c15]   = f2bf(e1*inv);
        }
      // PV (K=32)
      f32x4 oac[2][4];
      #pragma unroll
      for (int nt=0;nt<4;nt++){
        s16x8 bb;
        #pragma unroll
        for (int e=0;e<8;e++) bb[e] = (short)qb[g4*8+e][512 + h*HDh + nt*16 + c15];
        #pragma unroll
        for (int mt=0;mt<2;mt++){
          f32x4 acc = {0.f,0.f,0.f,0.f};
          s16x8 a = *(const s16x8*)&pb[h][mt*16+c15][g4*8];
          acc = mfma16(a, bb, acc);
          oac[mt][nt] = acc;
        }
      }
      __syncthreads();   // qkv fully consumed; xn free for attn-out
      #pragma unroll
      for (int mt=0;mt<2;mt++)
        #pragma unroll
        for (int nt=0;nt<4;nt++)
          #pragma unroll
          for (int r=0;r<4;r++)
            xn[mt*16 + g4*4 + r][h*HDh + nt*16 + c15] = f2bf(oac[mt][nt][r]);
    }
    __syncthreads();
    // ---- out-proj GEMM (K=256), accumulate into xs ----
    const u16* Wo = opwb + (size_t)l*NC*NC;
    const float* bo = opb + l*NC;
    for (int tt=wid; tt<32; tt+=4){
      int m0 = (tt & 1)*16, n0 = (tt >> 1)*16;
      f32x4 acc = {0.f,0.f,0.f,0.f};
      #pragma unroll
      for (int kk=0;kk<8;kk++){
        s16x8 a = *(const s16x8*)&xn[m0+c15][kk*32 + g4*8];
        s16x8 bb = *(const s16x8*)&Wo[(size_t)(n0+c15)*NC + kk*32 + g4*8];
        acc = mfma16(a, bb, acc);
      }
      int col = n0 + c15;
      float bias = bo[col];
      #pragma unroll
      for (int r=0;r<4;r++) xs[m0 + g4*4 + r][col] += acc[r] + bias;
    }
    __syncthreads();
    // ---- LN2 ----
    ln_block(xs, xn, ln2s + l*NC, ln2b + l*NC, t);
    __syncthreads();
    // ---- FF1 (K=256 -> 512 cols, relu) into qb ----
    const u16* W1 = fc1wb + (size_t)l*NDFF*NC;
    for (int tt=wid; tt<64; tt+=4){
      int m0 = (tt & 1)*16, n0 = (tt >> 1)*16;
      f32x4 acc = {0.f,0.f,0.f,0.f};
      #pragma unroll
      for (int kk=0;kk<8;kk++){
        s16x8 a = *(const s16x8*)&xn[m0+c15][kk*32 + g4*8];
        s16x8 bb = *(const s16x8*)&W1[(size_t)(n0+c15)*NC + kk*32 + g4*8];
        acc = mfma16(a, bb, acc);
      }
      int col = n0 + c15;
      float bias = fc1b[l*NDFF + col];
      #pragma unroll
      for (int r=0;r<4;r++){
        float v = acc[r] + bias;
        qb[m0 + g4*4 + r][col] = f2bf(v > 0.f ? v : 0.f);
      }
    }
    __syncthreads();
    // ---- FF2 (K=512), accumulate into xs ----
    const u16* W2 = fc2wb + (size_t)l*NC*NDFF;
    for (int tt=wid; tt<32; tt+=4){
      int m0 = (tt & 1)*16, n0 = (tt >> 1)*16;
      f32x4 acc = {0.f,0.f,0.f,0.f};
      #pragma unroll
      for (int kk=0;kk<16;kk++){
        s16x8 a = *(const s16x8*)&qb[m0+c15][kk*32 + g4*8];
        s16x8 bb = *(const s16x8*)&W2[(size_t)(n0+c15)*NDFF + kk*32 + g4*8];
        acc = mfma16(a, bb, acc);
      }
      int col = n0 + c15;
      float bias = fc2b[l*NC + col];
      #pragma unroll
      for (int r=0;r<4;r++) xs[m0 + g4*4 + r][col] += acc[r] + bias;
    }
    __syncthreads();
  }
  // ---- scatter winners ----
  for (int s=0;s<32;s++){
    int n = idx_sh[s];
    if (firstg[b*NN + n] == p*NSs + s)
      out[((size_t)b*NN + n)*NC + t] = xs[s][t];
  }
}

extern "C" void kernel_launch(void* const* d_in, const int* in_sizes, int n_in,
                              void* d_out, int out_size, void* d_ws, size_t ws_size,
                              hipStream_t stream){
  const float* xyz   = (const float*)d_in[0];
  const float* feat  = (const float*)d_in[1];
  const float* pe1w  = (const float*)d_in[2];
  const float* pe1b  = (const float*)d_in[3];
  const float* bng   = (const float*)d_in[4];
  const float* bnb   = (const float*)d_in[5];
  const float* bnm   = (const float*)d_in[6];
  const float* bnv   = (const float*)d_in[7];
  const float* pe2w  = (const float*)d_in[8];
  const float* pe2b  = (const float*)d_in[9];
  const float* ipw   = (const float*)d_in[10];
  const float* ipb   = (const float*)d_in[11];
  const float* opw   = (const float*)d_in[12];
  const float* opb   = (const float*)d_in[13];
  const float* ln1s  = (const float*)d_in[14];
  const float* ln1b  = (const float*)d_in[15];
  const float* ln2s  = (const float*)d_in[16];
  const float* ln2b  = (const float*)d_in[17];
  const float* fc1w  = (const float*)d_in[18];
  const float* fc1b  = (const float*)d_in[19];
  const float* fc2w  = (const float*)d_in[20];
  const float* fc2b  = (const float*)d_in[21];
  float* out = (float*)d_out;

  char* ws = (char*)d_ws;
  size_t off = 0;
  auto alloc = [&](size_t bytes)->void*{
    void* p = ws + off;
    off = (off + bytes + 255) & ~(size_t)255;
    return p;
  };
  int*   fps_idx = (int*)  alloc((size_t)NB*NPp*4);
  float* newxyz  = (float*)alloc((size_t)NB*NPp*3*4);
  int*   idxg    = (int*)  alloc((size_t)NB*NPp*NSs*4);
  int*   first   = (int*)  alloc((size_t)NB*NN*4);
  float* bnsc    = (float*)alloc(128*4);
  float* bnsh    = (float*)alloc(128*4);
  u16*   ipwb    = (u16*)  alloc((size_t)NL*768*NC*2);
  u16*   opwb    = (u16*)  alloc((size_t)NL*NC*NC*2);
  u16*   fc1wb   = (u16*)  alloc((size_t)NL*NDFF*NC*2);
  u16*   fc2wb   = (u16*)  alloc((size_t)NL*NC*NDFF*2);
  u16*   pe2wb   = (u16*)  alloc((size_t)NC*128*2);
  float* featT   = (float*)(ws + off);
  int useT = (off + (size_t)NB*NN*NC*4 <= ws_size) ? 1 : 0;

  k_prep<<<512, 256, 0, stream>>>(ipw, opw, fc1w, fc2w, pe2w, bng, bnb, bnm, bnv,
                                  ipwb, opwb, fc1wb, fc2wb, pe2wb, bnsc, bnsh, first);
  k_fps<<<NB, 1024, 0, stream>>>(xyz, fps_idx, newxyz);
  k_ballq<<<(NB*NPp)/4, 256, 0, stream>>>(xyz, newxyz, idxg);
  k_first<<<(NB*NPp*NSs)/256, 256, 0, stream>>>(idxg, first);
  k_outinit<<<dim3(NN/32, NB), 256, 0, stream>>>(feat, first, out, featT, useT);
  k_tf<<<NB*NPp, 256, 0, stream>>>(xyz, feat, featT, useT, idxg, newxyz, first,
                                   pe1w, pe1b, bnsc, bnsh, pe2wb, pe2b,
                                   ipwb, ipb, opwb, opb, ln1s, ln1b, ln2s, ln2b,
                                   fc1wb, fc1b, fc2wb, fc2b, out);
  (void)in_sizes; (void)n_in; (void)out_size;
}

// Round 4
// 6428.934 us; speedup vs baseline: 1.1628x; 1.0031x over previous
//
#include <hip/hip_runtime.h>

#define NB 2
#define NN 16384
#define NC 256
#define NPp 2048
#define NSs 32
#define NH 4
#define HDh 64
#define NL 2
#define NDFF 512
#define LFv (NPp*NSs)
#define LNEPS 1e-5f

typedef short s16x8 __attribute__((ext_vector_type(8)));
typedef float f32x4 __attribute__((ext_vector_type(4)));
typedef float f32x2 __attribute__((ext_vector_type(2)));
typedef unsigned short u16;

__device__ __forceinline__ u16 f2bf(float f){
  unsigned u = __float_as_uint(f);
  u += 0x7fffu + ((u>>16)&1u);
  return (u16)(u>>16);
}

__device__ __forceinline__ f32x4 mfma16(s16x8 a, s16x8 b, f32x4 c){
  return __builtin_amdgcn_mfma_f32_16x16x32_bf16(a, b, c, 0, 0, 0);
}

// packed f32 ops (component-wise IEEE identical to scalar; no fma fusion)
__device__ __forceinline__ f32x2 pk_add(f32x2 a, f32x2 b){
  f32x2 d; asm("v_pk_add_f32 %0, %1, %2" : "=v"(d) : "v"(a), "v"(b)); return d;
}
__device__ __forceinline__ f32x2 pk_mul(f32x2 a, f32x2 b){
  f32x2 d; asm("v_pk_mul_f32 %0, %1, %2" : "=v"(d) : "v"(a), "v"(b)); return d;
}

// DPP-based fmax step: v = fmax(v, dpp_shuffle(v)); fmax exact -> selection-safe
#define DPP_FMAX(v, ctrl) do { \
  int _iv = __float_as_int(v); \
  int _sh = __builtin_amdgcn_update_dpp(_iv, _iv, (ctrl), 0xF, 0xF, false); \
  (v) = fmaxf((v), __int_as_float(_sh)); \
} while(0)

// ---------------- prep: bf16 weights, first[] init, bn fold ----------------
__global__ void k_prep(const float* __restrict__ ipw, const float* __restrict__ opw,
                       const float* __restrict__ fc1w, const float* __restrict__ fc2w,
                       const float* __restrict__ pe2w,
                       const float* __restrict__ bng, const float* __restrict__ bnb,
                       const float* __restrict__ bnm, const float* __restrict__ bnv,
                       u16* ipwb, u16* opwb, u16* fc1wb, u16* fc2wb, u16* pe2wb,
                       float* bnsc, float* bnsh, int* first){
  const int i0 = blockIdx.x*blockDim.x + threadIdx.x;
  const int stride = gridDim.x*blockDim.x;
  for (int i=i0; i<NL*768*NC; i+=stride) ipwb[i] = f2bf(ipw[i]);
  for (int i=i0; i<NL*NC*NC; i+=stride)  opwb[i] = f2bf(opw[i]);
  for (int i=i0; i<NL*NDFF*NC; i+=stride) fc1wb[i] = f2bf(fc1w[i]);
  for (int i=i0; i<NL*NC*NDFF; i+=stride) fc2wb[i] = f2bf(fc2w[i]);
  for (int i=i0; i<NC*128; i+=stride)    pe2wb[i] = f2bf(pe2w[i]);
  for (int i=i0; i<NB*NN; i+=stride)     first[i] = LFv;
  for (int i=i0; i<128; i+=stride){
    float sc = bng[i]*rsqrtf(bnv[i]+LNEPS);
    bnsc[i] = sc; bnsh[i] = bnb[i] - bnm[i]*sc;
  }
}

// ---------------- FPS: one block per batch, 1 barrier per step -------------
// Latency-optimized: DPP wave-max, ballot+SALU argmax, pre-barrier coord
// prefetch into double-buffered LDS (no post-barrier global load).
__global__ __launch_bounds__(1024,1) void k_fps(const float* __restrict__ xyz,
                                                int* fps_idx, float* newxyz){
#pragma clang fp contract(off)
  const int b = blockIdx.x;
  const int t = threadIdx.x;
  const int lane = t & 63, wid = t >> 6;
  const int wbase = wid*64;
  const float* xb = xyz + (size_t)b*NN*3;
  // pair layout: pair m holds points t+(2m)*1024 (.x) and t+(2m+1)*1024 (.y)
  f32x2 px2[8], py2[8], pz2[8], dd2[8];
  #pragma unroll
  for (int m=0;m<8;m++){
    int i0 = t + (2*m)*1024, i1 = t + (2*m+1)*1024;
    px2[m] = f32x2{xb[i0*3],   xb[i1*3]};
    py2[m] = f32x2{xb[i0*3+1], xb[i1*3+1]};
    pz2[m] = f32x2{xb[i0*3+2], xb[i1*3+2]};
    dd2[m] = f32x2{1e10f, 1e10f};
  }
  __shared__ unsigned long long keybuf[4];
  __shared__ float wcoord[2][16][4];
  if (t < 4) keybuf[t] = 0ull;
  float wx = xb[0], wy = xb[1], wz = xb[2];
  if (t==0){
    fps_idx[b*NPp] = 0;
    newxyz[(size_t)b*NPp*3+0]=wx;
    newxyz[(size_t)b*NPp*3+1]=wy;
    newxyz[(size_t)b*NPp*3+2]=wz;
  }
  float ncx = -wx, ncy = -wy, ncz = -wz;
  __syncthreads();
  for (int step=1; step<NPp; ++step){
    const f32x2 ncx2 = {ncx,ncx}, ncy2 = {ncy,ncy}, ncz2 = {ncz,ncz};
    // hot loop: exact ((dx*dx+dy*dy)+dz*dz), packed 2 pts/instr
    #pragma unroll
    for (int m=0;m<8;m++){
      f32x2 dx = pk_add(px2[m], ncx2);
      f32x2 dy = pk_add(py2[m], ncy2);
      f32x2 dz = pk_add(pz2[m], ncz2);
      f32x2 s  = pk_add(pk_add(pk_mul(dx,dx), pk_mul(dy,dy)), pk_mul(dz,dz));
      f32x2 d  = dd2[m];
      d.x = fminf(d.x, s.x);
      d.y = fminf(d.y, s.y);
      dd2[m] = d;
    }
    // per-thread max (max3-fusable nesting; fmax exact)
    float a0 = fmaxf(fmaxf(dd2[0].x, dd2[0].y), dd2[1].x);
    float a1 = fmaxf(fmaxf(dd2[1].y, dd2[2].x), dd2[2].y);
    float a2 = fmaxf(fmaxf(dd2[3].x, dd2[3].y), dd2[4].x);
    float a3 = fmaxf(fmaxf(dd2[4].y, dd2[5].x), dd2[5].y);
    float a4 = fmaxf(fmaxf(dd2[6].x, dd2[6].y), dd2[7].x);
    float M  = fmaxf(fmaxf(fmaxf(a0, a1), fmaxf(a2, a3)), fmaxf(a4, dd2[7].y));
    // wave max via DPP (row_shr 1,2,4,8 then bcast15, bcast31 -> lane63)
    DPP_FMAX(M, 0x111);
    DPP_FMAX(M, 0x112);
    DPP_FMAX(M, 0x114);
    DPP_FMAX(M, 0x118);
    DPP_FMAX(M, 0x142);
    DPP_FMAX(M, 0x143);
    const unsigned Mb = (unsigned)__builtin_amdgcn_readlane(__float_as_int(M), 63);
    const float Ms = __int_as_float((int)Mb);
    // ballot per slice, SALU min-index pick (j-major == global-index order)
    unsigned long long bl[8], bh[8];
    #pragma unroll
    for (int m=0;m<8;m++){
      bl[m] = __ballot(dd2[m].x == Ms);
      bh[m] = __ballot(dd2[m].y == Ms);
    }
    int idx = 0x7fffffff;
    #pragma unroll
    for (int m=7;m>=0;m--){
      if (bh[m]) idx = (2*m+1)*1024 + wbase + (__ffsll((unsigned long long)bh[m])-1);
      if (bl[m]) idx = (2*m)*1024   + wbase + (__ffsll((unsigned long long)bl[m])-1);
    }
    const int buf2 = step & 1;
    if (lane==0){
      unsigned long long key = ((unsigned long long)Mb << 32)
                             | (unsigned)(0x7fffffff - idx);
      atomicMax(&keybuf[step & 3], key);
      // prefetch THIS wave's candidate coords (overlapped across waves)
      const float* cp = xb + (size_t)idx*3;
      float q0 = cp[0], q1 = cp[1], q2 = cp[2];
      wcoord[buf2][wid][0] = q0;
      wcoord[buf2][wid][1] = q1;
      wcoord[buf2][wid][2] = q2;
    }
    __syncthreads();   // the ONLY barrier per step
    const unsigned long long kk = keybuf[step & 3];
    const int widx = 0x7fffffff - (int)(unsigned)(kk & 0xffffffffu);
    const int wwave = (widx & 1023) >> 6;
    const float nx = wcoord[buf2][wwave][0];
    const float ny = wcoord[buf2][wwave][1];
    const float nz = wcoord[buf2][wwave][2];
    ncx = -nx; ncy = -ny; ncz = -nz;
    if (t==0){
      fps_idx[b*NPp + step] = widx;
      newxyz[((size_t)b*NPp+step)*3+0]=nx;
      newxyz[((size_t)b*NPp+step)*3+1]=ny;
      newxyz[((size_t)b*NPp+step)*3+2]=nz;
      keybuf[(step+2) & 3] = 0ull;   // reset at distance 2 (race-free)
    }
  }
}

// ---------------- ball query: one wave per center ---------------------------
__global__ __launch_bounds__(256) void k_ballq(const float* __restrict__ xyz,
                                               const float* __restrict__ newxyz,
                                               int* __restrict__ idxg){
#pragma clang fp contract(off)
  const int gw = (blockIdx.x*256 + threadIdx.x) >> 6;
  const int lane = threadIdx.x & 63;
  if (gw >= NB*NPp) return;
  const int b = gw / NPp;
  const float cx=newxyz[(size_t)gw*3], cy=newxyz[(size_t)gw*3+1], cz=newxyz[(size_t)gw*3+2];
  const float* xb = xyz + (size_t)b*NN*3;
  int* op = idxg + (size_t)gw*NSs;
  int count = 0;
  int first_i = 0;
  for (int base=0; base<NN; base+=64){
    const int i = base + lane;
    float dx=xb[i*3]-cx, dy=xb[i*3+1]-cy, dz=xb[i*3+2]-cz;
    float d2=(dx*dx+dy*dy)+dz*dz;
    bool hit = d2 < 1.0f;
    unsigned long long m = __ballot(hit);
    if (m){
      int rank = __popcll(m & ((1ull<<lane)-1ull));
      int slot = count + rank;
      if (hit && slot < NSs) op[slot] = i;
      if (count == 0) first_i = base + (__ffsll((unsigned long long)m)-1);
      count += __popcll(m);
      if (count >= NSs) break;
    }
  }
  if (count < NSs){
    if (lane >= count && lane < NSs) op[lane] = (count>0) ? first_i : 0;
  }
}

// ---------------- first-occurrence (segment_min of flat pos) ---------------
__global__ void k_first(const int* __restrict__ idxg, int* __restrict__ first){
  int i = blockIdx.x*blockDim.x + threadIdx.x;
  if (i < NB*NPp*NSs){
    int b = i / (NPp*NSs);
    int pos = i % (NPp*NSs);
    atomicMin(&first[b*NN + idxg[i]], pos);
  }
}

// ---------------- transpose features -> out (non-winners) + featT ----------
__global__ __launch_bounds__(256) void k_outinit(const float* __restrict__ feat,
                                                 const int* __restrict__ first,
                                                 float* __restrict__ out,
                                                 float* __restrict__ featT, int useT){
  __shared__ float T[32][33];
  const int b = blockIdx.y;
  const int n0 = blockIdx.x*32;
  const int t = threadIdx.x;
  const int tn = t & 31, tc = t >> 5;          // tc in 0..7
  for (int cb=0; cb<NC; cb+=32){
    #pragma unroll
    for (int i=0;i<32;i+=8)
      T[tc+i][tn] = feat[((size_t)b*NC + cb+tc+i)*NN + n0+tn];
    __syncthreads();
    #pragma unroll
    for (int i=0;i<32;i+=8){
      int n = n0 + tc + i;
      float v = T[tn][tc+i];
      if (useT) featT[((size_t)b*NN + n)*NC + cb+tn] = v;
      if (first[b*NN+n] == LFv) out[((size_t)b*NN + n)*NC + cb+tn] = v;
    }
    __syncthreads();
  }
}

// ---------------- fused group + PE + 2-layer transformer + scatter ---------
__device__ __forceinline__ void ln_block(float (*xs)[NC], u16 (*xn)[264],
                                         const float* __restrict__ s_,
                                         const float* __restrict__ b_, int t){
  const int s = t >> 3, j = t & 7;            // 8 threads per row
  float v[32];
  float sum = 0.f;
  #pragma unroll
  for (int k=0;k<32;k++){ v[k]=xs[s][j*32+k]; sum += v[k]; }
  #pragma unroll
  for (int m=1;m<8;m<<=1) sum += __shfl_xor(sum, m);
  const float mean = sum * (1.f/256.f);
  float vs = 0.f;
  #pragma unroll
  for (int k=0;k<32;k++){ float d=v[k]-mean; vs += d*d; }
  #pragma unroll
  for (int m=1;m<8;m<<=1) vs += __shfl_xor(vs, m);
  const float rstd = rsqrtf(vs*(1.f/256.f) + LNEPS);
  #pragma unroll
  for (int k=0;k<32;k++){
    int c = j*32+k;
    float y = (v[k]-mean)*rstd*s_[c] + b_[c];
    xs[s][c] = y;
    xn[s][c] = f2bf(y);
  }
}

__global__ __launch_bounds__(256,1) void k_tf(
    const float* __restrict__ xyz, const float* __restrict__ features,
    const float* __restrict__ featT, int useT,
    const int* __restrict__ idxg, const float* __restrict__ newxyz,
    const int* __restrict__ firstg,
    const float* __restrict__ pe1w, const float* __restrict__ pe1b,
    const float* __restrict__ bnsc, const float* __restrict__ bnsh,
    const u16* __restrict__ pe2wb, const float* __restrict__ pe2b,
    const u16* __restrict__ ipwb, const float* __restrict__ ipb,
    const u16* __restrict__ opwb, const float* __restrict__ opb,
    const float* __restrict__ ln1s, const float* __restrict__ ln1b,
    const float* __restrict__ ln2s, const float* __restrict__ ln2b,
    const u16* __restrict__ fc1wb, const float* __restrict__ fc1b,
    const u16* __restrict__ fc2wb, const float* __restrict__ fc2b,
    float* __restrict__ out){
  __shared__ float xs[32][NC];        // residual stream (fp32)
  __shared__ u16  xn[32][264];        // LN output / attn-out (bf16, A operand)
  __shared__ u16  qb[32][776];        // qkv (bf16), reused as FF hidden
  __shared__ u16  pb[NH][32][40];     // softmax P per head
  __shared__ int  idx_sh[32];
  __shared__ float gx_sh[32][3];

  const int seq = blockIdx.x;
  const int b = seq / NPp, p = seq % NPp;
  const int t = threadIdx.x, lane = t & 63, wid = t >> 6;
  const int c15 = lane & 15, g4 = lane >> 4;

  if (t < 32) idx_sh[t] = idxg[(size_t)seq*NSs + t];
  __syncthreads();
  if (t < 96){
    int s = t/3, d = t%3;
    gx_sh[s][d] = xyz[((size_t)b*NN + idx_sh[s])*3 + d] - newxyz[(size_t)seq*3 + d];
  }
  if (useT){
    for (int s=0;s<32;s++) xs[s][t] = featT[((size_t)b*NN + idx_sh[s])*NC + t];
  } else {
    for (int s=0;s<32;s++) xs[s][t] = features[((size_t)b*NC + t)*NN + idx_sh[s]];
  }
  __syncthreads();
  // PE conv1: h[32][128] bf16 into xn
  for (int i=t; i<32*128; i+=256){
    int s = i >> 7, o = i & 127;
    float h = pe1w[o*3]*gx_sh[s][0] + pe1w[o*3+1]*gx_sh[s][1] + pe1w[o*3+2]*gx_sh[s][2] + pe1b[o];
    h = h*bnsc[o] + bnsh[o];
    xn[s][o] = f2bf(h > 0.f ? h : 0.f);
  }
  __syncthreads();
  // PE conv2 GEMM (K=128): xs += h @ pe2w^T + pe2b
  for (int tt = wid; tt < 32; tt += 4){
    int m0 = (tt & 1)*16, n0 = (tt >> 1)*16;
    f32x4 acc = {0.f,0.f,0.f,0.f};
    #pragma unroll
    for (int kk=0; kk<4; kk++){
      s16x8 a = *(const s16x8*)&xn[m0+c15][kk*32 + g4*8];
      s16x8 bb = *(const s16x8*)&pe2wb[(size_t)(n0+c15)*128 + kk*32 + g4*8];
      acc = mfma16(a, bb, acc);
    }
    int col = n0 + c15;
    float bias = pe2b[col];
    #pragma unroll
    for (int r=0;r<4;r++) xs[m0 + g4*4 + r][col] += acc[r] + bias;
  }
  __syncthreads();

  for (int l=0; l<NL; ++l){
    // ---- LN1 ----
    ln_block(xs, xn, ln1s + l*NC, ln1b + l*NC, t);
    __syncthreads();
    // ---- QKV GEMM (K=256 -> 768 cols) ----
    const u16* Wq = ipwb + (size_t)l*768*NC;
    const float* bq = ipb + l*768;
    for (int tt=wid; tt<96; tt+=4){
      int m0 = (tt & 1)*16, n0 = (tt >> 1)*16;
      f32x4 acc = {0.f,0.f,0.f,0.f};
      #pragma unroll
      for (int kk=0;kk<8;kk++){
        s16x8 a = *(const s16x8*)&xn[m0+c15][kk*32 + g4*8];
        s16x8 bb = *(const s16x8*)&Wq[(size_t)(n0+c15)*NC + kk*32 + g4*8];
        acc = mfma16(a, bb, acc);
      }
      int col = n0 + c15;
      float bias = bq[col];
      #pragma unroll
      for (int r=0;r<4;r++) qb[m0 + g4*4 + r][col] = f2bf(acc[r] + bias);
    }
    __syncthreads();
    // ---- attention: wave = head ----
    {
      const int h = wid;
      f32x4 lac[2][2];
      #pragma unroll
      for (int mt=0;mt<2;mt++)
        #pragma unroll
        for (int nt=0;nt<2;nt++){
          f32x4 acc = {0.f,0.f,0.f,0.f};
          #pragma unroll
          for (int kk=0;kk<2;kk++){
            s16x8 a = *(const s16x8*)&qb[mt*16+c15][h*HDh + kk*32 + g4*8];
            s16x8 bb = *(const s16x8*)&qb[nt*16+c15][256 + h*HDh + kk*32 + g4*8];
            acc = mfma16(a, bb, acc);
          }
          lac[mt][nt] = acc;
        }
      #pragma unroll
      for (int mt=0;mt<2;mt++)
        #pragma unroll
        for (int r=0;r<4;r++){
          float v0 = lac[mt][0][r]*0.125f, v1 = lac[mt][1][r]*0.125f;
          float mx = fmaxf(v0, v1);
          #pragma unroll
          for (int m=1;m<16;m<<=1) mx = fmaxf(mx, __shfl_xor(mx, m));
          float e0 = expf(v0-mx), e1 = expf(v1-mx);
          float sm = e0 + e1;
          #pragma unroll
          for (int m=1;m<16;m<<=1) sm += __shfl_xor(sm, m);
          float inv = 1.f/sm;
          int row = mt*16 + g4*4 + r;
          pb[h][row][c15]      = f2bf(e0*inv);
          pb[h][row][16+c15]   = f2bf(e1*inv);
        }
      // PV (K=32)
      f32x4 oac[2][4];
      #pragma unroll
      for (int nt=0;nt<4;nt++){
        s16x8 bb;
        #pragma unroll
        for (int e=0;e<8;e++) bb[e] = (short)qb[g4*8+e][512 + h*HDh + nt*16 + c15];
        #pragma unroll
        for (int mt=0;mt<2;mt++){
          f32x4 acc = {0.f,0.f,0.f,0.f};
          s16x8 a = *(const s16x8*)&pb[h][mt*16+c15][g4*8];
          acc = mfma16(a, bb, acc);
          oac[mt][nt] = acc;
        }
      }
      __syncthreads();   // qkv fully consumed; xn free for attn-out
      #pragma unroll
      for (int mt=0;mt<2;mt++)
        #pragma unroll
        for (int nt=0;nt<4;nt++)
          #pragma unroll
          for (int r=0;r<4;r++)
            xn[mt*16 + g4*4 + r][h*HDh + nt*16 + c15] = f2bf(oac[mt][nt][r]);
    }
    __syncthreads();
    // ---- out-proj GEMM (K=256), accumulate into xs ----
    const u16* Wo = opwb + (size_t)l*NC*NC;
    const float* bo = opb + l*NC;
    for (int tt=wid; tt<32; tt+=4){
      int m0 = (tt & 1)*16, n0 = (tt >> 1)*16;
      f32x4 acc = {0.f,0.f,0.f,0.f};
      #pragma unroll
      for (int kk=0;kk<8;kk++){
        s16x8 a = *(const s16x8*)&xn[m0+c15][kk*32 + g4*8];
        s16x8 bb = *(const s16x8*)&Wo[(size_t)(n0+c15)*NC + kk*32 + g4*8];
        acc = mfma16(a, bb, acc);
      }
      int col = n0 + c15;
      float bias = bo[col];
      #pragma unroll
      for (int r=0;r<4;r++) xs[m0 + g4*4 + r][col] += acc[r] + bias;
    }
    __syncthreads();
    // ---- LN2 ----
    ln_block(xs, xn, ln2s + l*NC, ln2b + l*NC, t);
    __syncthreads();
    // ---- FF1 (K=256 -> 512 cols, relu) into qb ----
    const u16* W1 = fc1wb + (size_t)l*NDFF*NC;
    for (int tt=wid; tt<64; tt+=4){
      int m0 = (tt & 1)*16, n0 = (tt >> 1)*16;
      f32x4 acc = {0.f,0.f,0.f,0.f};
      #pragma unroll
      for (int kk=0;kk<8;kk++){
        s16x8 a = *(const s16x8*)&xn[m0+c15][kk*32 + g4*8];
        s16x8 bb = *(const s16x8*)&W1[(size_t)(n0+c15)*NC + kk*32 + g4*8];
        acc = mfma16(a, bb, acc);
      }
      int col = n0 + c15;
      float bias = fc1b[l*NDFF + col];
      #pragma unroll
      for (int r=0;r<4;r++){
        float v = acc[r] + bias;
        qb[m0 + g4*4 + r][col] = f2bf(v > 0.f ? v : 0.f);
      }
    }
    __syncthreads();
    // ---- FF2 (K=512), accumulate into xs ----
    const u16* W2 = fc2wb + (size_t)l*NC*NDFF;
    for (int tt=wid; tt<32; tt+=4){
      int m0 = (tt & 1)*16, n0 = (tt >> 1)*16;
      f32x4 acc = {0.f,0.f,0.f,0.f};
      #pragma unroll
      for (int kk=0;kk<16;kk++){
        s16x8 a = *(const s16x8*)&qb[m0+c15][kk*32 + g4*8];
        s16x8 bb = *(const s16x8*)&W2[(size_t)(n0+c15)*NDFF + kk*32 + g4*8];
        acc = mfma16(a, bb, acc);
      }
      int col = n0 + c15;
      float bias = fc2b[l*NC + col];
      #pragma unroll
      for (int r=0;r<4;r++) xs[m0 + g4*4 + r][col] += acc[r] + bias;
    }
    __syncthreads();
  }
  // ---- scatter winners ----
  for (int s=0;s<32;s++){
    int n = idx_sh[s];
    if (firstg[b*NN + n] == p*NSs + s)
      out[((size_t)b*NN + n)*NC + t] = xs[s][t];
  }
}

extern "C" void kernel_launch(void* const* d_in, const int* in_sizes, int n_in,
                              void* d_out, int out_size, void* d_ws, size_t ws_size,
                              hipStream_t stream){
  const float* xyz   = (const float*)d_in[0];
  const float* feat  = (const float*)d_in[1];
  const float* pe1w  = (const float*)d_in[2];
  const float* pe1b  = (const float*)d_in[3];
  const float* bng   = (const float*)d_in[4];
  const float* bnb   = (const float*)d_in[5];
  const float* bnm   = (const float*)d_in[6];
  const float* bnv   = (const float*)d_in[7];
  const float* pe2w  = (const float*)d_in[8];
  const float* pe2b  = (const float*)d_in[9];
  const float* ipw   = (const float*)d_in[10];
  const float* ipb   = (const float*)d_in[11];
  const float* opw   = (const float*)d_in[12];
  const float* opb   = (const float*)d_in[13];
  const float* ln1s  = (const float*)d_in[14];
  const float* ln1b  = (const float*)d_in[15];
  const float* ln2s  = (const float*)d_in[16];
  const float* ln2b  = (const float*)d_in[17];
  const float* fc1w  = (const float*)d_in[18];
  const float* fc1b  = (const float*)d_in[19];
  const float* fc2w  = (const float*)d_in[20];
  const float* fc2b  = (const float*)d_in[21];
  float* out = (float*)d_out;

  char* ws = (char*)d_ws;
  size_t off = 0;
  auto alloc = [&](size_t bytes)->void*{
    void* p = ws + off;
    off = (off + bytes + 255) & ~(size_t)255;
    return p;
  };
  int*   fps_idx = (int*)  alloc((size_t)NB*NPp*4);
  float* newxyz  = (float*)alloc((size_t)NB*NPp*3*4);
  int*   idxg    = (int*)  alloc((size_t)NB*NPp*NSs*4);
  int*   first   = (int*)  alloc((size_t)NB*NN*4);
  float* bnsc    = (float*)alloc(128*4);
  float* bnsh    = (float*)alloc(128*4);
  u16*   ipwb    = (u16*)  alloc((size_t)NL*768*NC*2);
  u16*   opwb    = (u16*)  alloc((size_t)NL*NC*NC*2);
  u16*   fc1wb   = (u16*)  alloc((size_t)NL*NDFF*NC*2);
  u16*   fc2wb   = (u16*)  alloc((size_t)NL*NC*NDFF*2);
  u16*   pe2wb   = (u16*)  alloc((size_t)NC*128*2);
  float* featT   = (float*)(ws + off);
  int useT = (off + (size_t)NB*NN*NC*4 <= ws_size) ? 1 : 0;

  k_prep<<<512, 256, 0, stream>>>(ipw, opw, fc1w, fc2w, pe2w, bng, bnb, bnm, bnv,
                                  ipwb, opwb, fc1wb, fc2wb, pe2wb, bnsc, bnsh, first);
  k_fps<<<NB, 1024, 0, stream>>>(xyz, fps_idx, newxyz);
  k_ballq<<<(NB*NPp)/4, 256, 0, stream>>>(xyz, newxyz, idxg);
  k_first<<<(NB*NPp*NSs)/256, 256, 0, stream>>>(idxg, first);
  k_outinit<<<dim3(NN/32, NB), 256, 0, stream>>>(feat, first, out, featT, useT);
  k_tf<<<NB*NPp, 256, 0, stream>>>(xyz, feat, featT, useT, idxg, newxyz, first,
                                   pe1w, pe1b, bnsc, bnsh, pe2wb, pe2b,
                                   ipwb, ipb, opwb, opb, ln1s, ln1b, ln2s, ln2b,
                                   fc1wb, fc1b, fc2wb, fc2b, out);
  (void)in_sizes; (void)n_in; (void)out_size;
}

// Round 5
// 4473.650 us; speedup vs baseline: 1.6710x; 1.4371x over previous
//
#include <hip/hip_runtime.h>

#define NB 2
#define NN 16384
#define NC 256
#define NPp 2048
#define NSs 32
#define NH 4
#define HDh 64
#define NL 2
#define NDFF 512
#define LFv (NPp*NSs)
#define LNEPS 1e-5f
#define NBLK 256
#define NTHR 512

typedef short s16x8 __attribute__((ext_vector_type(8)));
typedef float f32x4 __attribute__((ext_vector_type(4)));
typedef float f32x2 __attribute__((ext_vector_type(2)));
typedef unsigned short u16;
typedef unsigned long long u64;

struct CtlBlock { int prog[2]; int ctr1; int ctr2; int bar; };

__device__ __forceinline__ u16 f2bf(float f){
  unsigned u = __float_as_uint(f);
  u += 0x7fffu + ((u>>16)&1u);
  return (u16)(u>>16);
}

__device__ __forceinline__ f32x4 mfma16(s16x8 a, s16x8 b, f32x4 c){
  return __builtin_amdgcn_mfma_f32_16x16x32_bf16(a, b, c, 0, 0, 0);
}

// packed f32 ops (component-wise IEEE identical to scalar; no fma fusion)
__device__ __forceinline__ f32x2 pk_add(f32x2 a, f32x2 b){
  f32x2 d; asm("v_pk_add_f32 %0, %1, %2" : "=v"(d) : "v"(a), "v"(b)); return d;
}
__device__ __forceinline__ f32x2 pk_mul(f32x2 a, f32x2 b){
  f32x2 d; asm("v_pk_mul_f32 %0, %1, %2" : "=v"(d) : "v"(a), "v"(b)); return d;
}

#define DPP_FMAX(v, ctrl) do { \
  int _iv = __float_as_int(v); \
  int _sh = __builtin_amdgcn_update_dpp(_iv, _iv, (ctrl), 0xF, 0xF, false); \
  (v) = fmaxf((v), __int_as_float(_sh)); \
} while(0)

#define DPP_IMIN(v, ctrl) do { \
  int _sh = __builtin_amdgcn_update_dpp((v), (v), (ctrl), 0xF, 0xF, false); \
  (v) = (_sh < (v)) ? _sh : (v); \
} while(0)

struct SMem {
  u64  masks[256];          // ballq chunk masks
  u64  keybuf[4];           // fps
  float xs[32][NC];         // residual (fp32)
  u16  xn[32][264];         // LN out / attn-out (bf16)
  u16  qb[32][776];         // qkv / FF hidden (bf16)
  u16  pb[NH][32][40];      // softmax P
  int  idx_sh[32];
  float gx_sh[32][3];
  float wcoord[2][8][4];    // fps candidate coords
  int  misc[16];
  int  win[32];
};

// ---------------- prep: bf16 weights, first[] init, ctl init ---------------
__global__ void k_prep(const float* __restrict__ ipw, const float* __restrict__ opw,
                       const float* __restrict__ fc1w, const float* __restrict__ fc2w,
                       const float* __restrict__ pe2w,
                       const float* __restrict__ bng, const float* __restrict__ bnb,
                       const float* __restrict__ bnm, const float* __restrict__ bnv,
                       u16* ipwb, u16* opwb, u16* fc1wb, u16* fc2wb, u16* pe2wb,
                       float* bnsc, float* bnsh, int* first, CtlBlock* ctl){
  const int i0 = blockIdx.x*blockDim.x + threadIdx.x;
  const int stride = gridDim.x*blockDim.x;
  for (int i=i0; i<NL*768*NC; i+=stride) ipwb[i] = f2bf(ipw[i]);
  for (int i=i0; i<NL*NC*NC; i+=stride)  opwb[i] = f2bf(opw[i]);
  for (int i=i0; i<NL*NDFF*NC; i+=stride) fc1wb[i] = f2bf(fc1w[i]);
  for (int i=i0; i<NL*NC*NDFF; i+=stride) fc2wb[i] = f2bf(fc2w[i]);
  for (int i=i0; i<NC*128; i+=stride)    pe2wb[i] = f2bf(pe2w[i]);
  for (int i=i0; i<NB*NN; i+=stride)     first[i] = LFv;
  for (int i=i0; i<128; i+=stride){
    float sc = bng[i]*rsqrtf(bnv[i]+LNEPS);
    bnsc[i] = sc; bnsh[i] = bnb[i] - bnm[i]*sc;
  }
  if (i0 == 0){
    ctl->prog[0] = -1; ctl->prog[1] = -1;
    ctl->ctr1 = 0; ctl->ctr2 = 0; ctl->bar = 0;
  }
}

// ---------------- featT: transpose features [B,C,N] -> [B,N,C] -------------
__global__ __launch_bounds__(256) void k_featT(const float* __restrict__ feat,
                                               float* __restrict__ featT){
  __shared__ float T[32][33];
  const int b = blockIdx.y;
  const int n0 = blockIdx.x*32;
  const int t = threadIdx.x;
  const int tn = t & 31, tc = t >> 5;
  for (int cb=0; cb<NC; cb+=32){
    #pragma unroll
    for (int i=0;i<32;i+=8)
      T[tc+i][tn] = feat[((size_t)b*NC + cb+tc+i)*NN + n0+tn];
    __syncthreads();
    #pragma unroll
    for (int i=0;i<32;i+=8)
      featT[((size_t)b*NN + n0+tc+i)*NC + cb+tn] = T[tn][tc+i];
    __syncthreads();
  }
}

// ---------------- FPS role (2 blocks, 512 threads, 32 pts/thread) ----------
__device__ void fps_run(int b, const float* __restrict__ xyz,
                        float* __restrict__ newxyz, CtlBlock* ctl, SMem& sm){
#pragma clang fp contract(off)
  const int t = threadIdx.x;
  const int lane = t & 63, wid = t >> 6;
  const float* xb = xyz + (size_t)b*NN*3;
  f32x2 px2[16], py2[16], pz2[16], dd2[16];
  #pragma unroll
  for (int m=0;m<16;m++){
    int i0 = t + (2*m)*NTHR, i1 = t + (2*m+1)*NTHR;
    px2[m] = f32x2{xb[i0*3],   xb[i1*3]};
    py2[m] = f32x2{xb[i0*3+1], xb[i1*3+1]};
    pz2[m] = f32x2{xb[i0*3+2], xb[i1*3+2]};
    dd2[m] = f32x2{1e10f, 1e10f};
  }
  if (t < 4) sm.keybuf[t] = 0ull;
  float wx = xb[0], wy = xb[1], wz = xb[2];
  if (t==0){
    newxyz[(size_t)b*NPp*3+0]=wx;
    newxyz[(size_t)b*NPp*3+1]=wy;
    newxyz[(size_t)b*NPp*3+2]=wz;
    __hip_atomic_store(&ctl->prog[b], 0, __ATOMIC_RELEASE, __HIP_MEMORY_SCOPE_AGENT);
  }
  float ncx=-wx, ncy=-wy, ncz=-wz;
  __syncthreads();
  for (int step=1; step<NPp; ++step){
    const f32x2 ncx2={ncx,ncx}, ncy2={ncy,ncy}, ncz2={ncz,ncz};
    #pragma unroll
    for (int m=0;m<16;m++){
      f32x2 dx = pk_add(px2[m], ncx2);
      f32x2 dy = pk_add(py2[m], ncy2);
      f32x2 dz = pk_add(pz2[m], ncz2);
      f32x2 s  = pk_add(pk_add(pk_mul(dx,dx), pk_mul(dy,dy)), pk_mul(dz,dz));
      f32x2 d  = dd2[m];
      d.x = fminf(d.x, s.x);
      d.y = fminf(d.y, s.y);
      dd2[m] = d;
    }
    float h8[8];
    #pragma unroll
    for (int q=0;q<8;q++)
      h8[q] = fmaxf(fmaxf(dd2[2*q].x, dd2[2*q].y), fmaxf(dd2[2*q+1].x, dd2[2*q+1].y));
    float M = fmaxf(fmaxf(fmaxf(h8[0],h8[1]),fmaxf(h8[2],h8[3])),
                    fmaxf(fmaxf(h8[4],h8[5]),fmaxf(h8[6],h8[7])));
    DPP_FMAX(M, 0x111); DPP_FMAX(M, 0x112); DPP_FMAX(M, 0x114); DPP_FMAX(M, 0x118);
    DPP_FMAX(M, 0x142); DPP_FMAX(M, 0x143);
    const unsigned Mb = (unsigned)__builtin_amdgcn_readlane(__float_as_int(M), 63);
    const float Ms = __int_as_float((int)Mb);
    int li = 0x7fffffff;
    #pragma unroll
    for (int m=15;m>=0;m--){
      if (dd2[m].y == Ms) li = t + (2*m+1)*NTHR;
      if (dd2[m].x == Ms) li = t + (2*m)*NTHR;
    }
    DPP_IMIN(li, 0x111); DPP_IMIN(li, 0x112); DPP_IMIN(li, 0x114); DPP_IMIN(li, 0x118);
    DPP_IMIN(li, 0x142); DPP_IMIN(li, 0x143);
    const int li63 = __builtin_amdgcn_readlane(li, 63);
    const int kb = step & 3, cb = step & 1;
    if (lane==0){
      u64 key = ((u64)Mb << 32) | (unsigned)(0x7fffffff - li63);
      atomicMax(&sm.keybuf[kb], key);
      const float* cp = xb + (size_t)li63*3;
      sm.wcoord[cb][wid][0]=cp[0]; sm.wcoord[cb][wid][1]=cp[1]; sm.wcoord[cb][wid][2]=cp[2];
    }
    __syncthreads();
    const u64 kk = sm.keybuf[kb];
    const int widx = 0x7fffffff - (int)(unsigned)(kk & 0xffffffffu);
    const int wv = (widx & (NTHR-1)) >> 6;
    const float nx = sm.wcoord[cb][wv][0];
    const float ny = sm.wcoord[cb][wv][1];
    const float nz = sm.wcoord[cb][wv][2];
    ncx=-nx; ncy=-ny; ncz=-nz;
    if (t==0){
      newxyz[((size_t)b*NPp+step)*3+0]=nx;
      newxyz[((size_t)b*NPp+step)*3+1]=ny;
      newxyz[((size_t)b*NPp+step)*3+2]=nz;
      sm.keybuf[(step+2)&3] = 0ull;
      if ((step & 7) == 7 || step == NPp-1)
        __hip_atomic_store(&ctl->prog[b], step, __ATOMIC_RELEASE, __HIP_MEMORY_SCOPE_AGENT);
    }
  }
}

// ---------------- inline ball query (512 threads) --------------------------
__device__ void seq_ballq(const float* __restrict__ xb, float cx, float cy, float cz,
                          SMem& sm, int t, int lane, int wid){
#pragma clang fp contract(off)
  for (int it=0; it<32; ++it){
    int cid = wid*32 + it;
    int i = cid*64 + lane;
    float dx=xb[i*3]-cx, dy=xb[i*3+1]-cy, dz=xb[i*3+2]-cz;
    float d2=(dx*dx+dy*dy)+dz*dz;
    u64 m = __ballot(d2 < 1.0f);
    if (lane==0) sm.masks[cid] = m;
  }
  __syncthreads();
  if (wid==0){
    u64 mk[4]; int cnt=0;
    #pragma unroll
    for (int j=0;j<4;j++){ mk[j]=sm.masks[lane*4+j]; cnt += __popcll(mk[j]); }
    int inc = cnt;
    #pragma unroll
    for (int ofs=1; ofs<64; ofs<<=1){
      int v = __shfl_up(inc, ofs);
      if (lane >= ofs) inc += v;
    }
    int r = inc - cnt;
    int tot = __shfl(inc, 63);
    #pragma unroll
    for (int j=0;j<4;j++){
      u64 msk = mk[j];
      int base = (lane*4+j)*64;
      while (msk && r < NSs){
        int bpos = __ffsll(msk)-1;
        sm.idx_sh[r] = base + bpos;
        msk &= msk-1;
        ++r;
      }
      if (r >= NSs) break;
    }
    int cc = tot < NSs ? tot : NSs;
    int pv = (tot > 0) ? sm.idx_sh[0] : 0;
    if (lane < NSs && lane >= cc) sm.idx_sh[lane] = pv;
  }
  __syncthreads();
}

// ---------------- LN over xs rows (512 threads, 16 thr/row) ----------------
__device__ __forceinline__ void ln_block512(SMem& sm, const float* __restrict__ s_,
                                            const float* __restrict__ b_, int t){
  const int s = t >> 4, j = t & 15;
  float v[16];
  float sum = 0.f;
  #pragma unroll
  for (int k=0;k<16;k++){ v[k]=sm.xs[s][j*16+k]; sum += v[k]; }
  #pragma unroll
  for (int m=1;m<16;m<<=1) sum += __shfl_xor(sum, m);
  const float mean = sum * (1.f/256.f);
  float vs = 0.f;
  #pragma unroll
  for (int k=0;k<16;k++){ float d=v[k]-mean; vs += d*d; }
  #pragma unroll
  for (int m=1;m<16;m<<=1) vs += __shfl_xor(vs, m);
  const float rstd = rsqrtf(vs*(1.f/256.f) + LNEPS);
  #pragma unroll
  for (int k=0;k<16;k++){
    int c = j*16+k;
    float y = (v[k]-mean)*rstd*s_[c] + b_[c];
    sm.xs[s][c] = y;
    sm.xn[s][c] = f2bf(y);
  }
}

// ---------------- PE + 2-layer transformer on one sequence ----------------
__device__ void seq_pe_tf(SMem& sm, int b, int p,
    const float* __restrict__ xyz, const float* __restrict__ features,
    const float* __restrict__ featT, int useT, const float* __restrict__ newxyz,
    const float* __restrict__ pe1w, const float* __restrict__ pe1b,
    const float* __restrict__ bnsc, const float* __restrict__ bnsh,
    const u16* __restrict__ pe2wb, const float* __restrict__ pe2b,
    const u16* __restrict__ ipwb, const float* __restrict__ ipb,
    const u16* __restrict__ opwb, const float* __restrict__ opb,
    const float* __restrict__ ln1s, const float* __restrict__ ln1b,
    const float* __restrict__ ln2s, const float* __restrict__ ln2b,
    const u16* __restrict__ fc1wb, const float* __restrict__ fc1b,
    const u16* __restrict__ fc2wb, const float* __restrict__ fc2b){
  const int t = threadIdx.x, lane = t & 63, wid = t >> 6;
  const int c15 = lane & 15, g4 = lane >> 4;

  if (t < 96){
    int s = t/3, d = t%3;
    sm.gx_sh[s][d] = xyz[((size_t)b*NN + sm.idx_sh[s])*3 + d] - newxyz[(size_t)p*3 + d];
  }
  if (useT){
    for (int e=t; e<32*NC; e+=NTHR){
      int s=e>>8, c=e&255;
      sm.xs[s][c] = featT[((size_t)b*NN + sm.idx_sh[s])*NC + c];
    }
  } else {
    for (int e=t; e<32*NC; e+=NTHR){
      int s=e>>8, c=e&255;
      sm.xs[s][c] = features[((size_t)b*NC + c)*NN + sm.idx_sh[s]];
    }
  }
  __syncthreads();
  // PE conv1
  for (int i=t; i<32*128; i+=NTHR){
    int s = i >> 7, o = i & 127;
    float h = pe1w[o*3]*sm.gx_sh[s][0] + pe1w[o*3+1]*sm.gx_sh[s][1] + pe1w[o*3+2]*sm.gx_sh[s][2] + pe1b[o];
    h = h*bnsc[o] + bnsh[o];
    sm.xn[s][o] = f2bf(h > 0.f ? h : 0.f);
  }
  __syncthreads();
  // PE conv2 (K=128)
  for (int tt=wid; tt<32; tt+=8){
    int m0 = (tt & 1)*16, n0 = (tt >> 1)*16;
    f32x4 acc = {0.f,0.f,0.f,0.f};
    #pragma unroll
    for (int kk=0; kk<4; kk++){
      s16x8 a = *(const s16x8*)&sm.xn[m0+c15][kk*32 + g4*8];
      s16x8 bb = *(const s16x8*)&pe2wb[(size_t)(n0+c15)*128 + kk*32 + g4*8];
      acc = mfma16(a, bb, acc);
    }
    int col = n0 + c15;
    float bias = pe2b[col];
    #pragma unroll
    for (int r=0;r<4;r++) sm.xs[m0 + g4*4 + r][col] += acc[r] + bias;
  }
  __syncthreads();

  for (int l=0; l<NL; ++l){
    ln_block512(sm, ln1s + l*NC, ln1b + l*NC, t);
    __syncthreads();
    // QKV (K=256 -> 768)
    const u16* Wq = ipwb + (size_t)l*768*NC;
    const float* bq = ipb + l*768;
    for (int tt=wid; tt<96; tt+=8){
      int m0 = (tt & 1)*16, n0 = (tt >> 1)*16;
      f32x4 acc = {0.f,0.f,0.f,0.f};
      #pragma unroll
      for (int kk=0;kk<8;kk++){
        s16x8 a = *(const s16x8*)&sm.xn[m0+c15][kk*32 + g4*8];
        s16x8 bb = *(const s16x8*)&Wq[(size_t)(n0+c15)*NC + kk*32 + g4*8];
        acc = mfma16(a, bb, acc);
      }
      int col = n0 + c15;
      float bias = bq[col];
      #pragma unroll
      for (int r=0;r<4;r++) sm.qb[m0 + g4*4 + r][col] = f2bf(acc[r] + bias);
    }
    __syncthreads();
    // attention: wave = (mt, head)
    {
      const int h = wid & 3;
      const int mt = wid >> 2;
      f32x4 lac[2];
      #pragma unroll
      for (int nt=0;nt<2;nt++){
        f32x4 acc = {0.f,0.f,0.f,0.f};
        #pragma unroll
        for (int kk=0;kk<2;kk++){
          s16x8 a = *(const s16x8*)&sm.qb[mt*16+c15][h*HDh + kk*32 + g4*8];
          s16x8 bb = *(const s16x8*)&sm.qb[nt*16+c15][256 + h*HDh + kk*32 + g4*8];
          acc = mfma16(a, bb, acc);
        }
        lac[nt] = acc;
      }
      #pragma unroll
      for (int r=0;r<4;r++){
        float v0 = lac[0][r]*0.125f, v1 = lac[1][r]*0.125f;
        float mx = fmaxf(v0, v1);
        #pragma unroll
        for (int m=1;m<16;m<<=1) mx = fmaxf(mx, __shfl_xor(mx, m));
        float e0 = expf(v0-mx), e1 = expf(v1-mx);
        float smm = e0 + e1;
        #pragma unroll
        for (int m=1;m<16;m<<=1) smm += __shfl_xor(smm, m);
        float inv = 1.f/smm;
        int row = mt*16 + g4*4 + r;
        sm.pb[h][row][c15]    = f2bf(e0*inv);
        sm.pb[h][row][16+c15] = f2bf(e1*inv);
      }
      // PV (K=32)
      f32x4 oac[4];
      #pragma unroll
      for (int nt=0;nt<4;nt++){
        s16x8 bb;
        #pragma unroll
        for (int e=0;e<8;e++) bb[e] = (short)sm.qb[g4*8+e][512 + h*HDh + nt*16 + c15];
        f32x4 acc = {0.f,0.f,0.f,0.f};
        s16x8 a = *(const s16x8*)&sm.pb[h][mt*16+c15][g4*8];
        oac[nt] = mfma16(a, bb, acc);
      }
      __syncthreads();
      #pragma unroll
      for (int nt=0;nt<4;nt++)
        #pragma unroll
        for (int r=0;r<4;r++)
          sm.xn[mt*16 + g4*4 + r][h*HDh + nt*16 + c15] = f2bf(oac[nt][r]);
    }
    __syncthreads();
    // out-proj (K=256)
    const u16* Wo = opwb + (size_t)l*NC*NC;
    const float* bo = opb + l*NC;
    for (int tt=wid; tt<32; tt+=8){
      int m0 = (tt & 1)*16, n0 = (tt >> 1)*16;
      f32x4 acc = {0.f,0.f,0.f,0.f};
      #pragma unroll
      for (int kk=0;kk<8;kk++){
        s16x8 a = *(const s16x8*)&sm.xn[m0+c15][kk*32 + g4*8];
        s16x8 bb = *(const s16x8*)&Wo[(size_t)(n0+c15)*NC + kk*32 + g4*8];
        acc = mfma16(a, bb, acc);
      }
      int col = n0 + c15;
      float bias = bo[col];
      #pragma unroll
      for (int r=0;r<4;r++) sm.xs[m0 + g4*4 + r][col] += acc[r] + bias;
    }
    __syncthreads();
    ln_block512(sm, ln2s + l*NC, ln2b + l*NC, t);
    __syncthreads();
    // FF1 (K=256 -> 512, relu)
    const u16* W1 = fc1wb + (size_t)l*NDFF*NC;
    for (int tt=wid; tt<64; tt+=8){
      int m0 = (tt & 1)*16, n0 = (tt >> 1)*16;
      f32x4 acc = {0.f,0.f,0.f,0.f};
      #pragma unroll
      for (int kk=0;kk<8;kk++){
        s16x8 a = *(const s16x8*)&sm.xn[m0+c15][kk*32 + g4*8];
        s16x8 bb = *(const s16x8*)&W1[(size_t)(n0+c15)*NC + kk*32 + g4*8];
        acc = mfma16(a, bb, acc);
      }
      int col = n0 + c15;
      float bias = fc1b[l*NDFF + col];
      #pragma unroll
      for (int r=0;r<4;r++){
        float v = acc[r] + bias;
        sm.qb[m0 + g4*4 + r][col] = f2bf(v > 0.f ? v : 0.f);
      }
    }
    __syncthreads();
    // FF2 (K=512)
    const u16* W2 = fc2wb + (size_t)l*NC*NDFF;
    for (int tt=wid; tt<32; tt+=8){
      int m0 = (tt & 1)*16, n0 = (tt >> 1)*16;
      f32x4 acc = {0.f,0.f,0.f,0.f};
      #pragma unroll
      for (int kk=0;kk<16;kk++){
        s16x8 a = *(const s16x8*)&sm.qb[m0+c15][kk*32 + g4*8];
        s16x8 bb = *(const s16x8*)&W2[(size_t)(n0+c15)*NDFF + kk*32 + g4*8];
        acc = mfma16(a, bb, acc);
      }
      int col = n0 + c15;
      float bias = fc2b[l*NC + col];
      #pragma unroll
      for (int r=0;r<4;r++) sm.xs[m0 + g4*4 + r][col] += acc[r] + bias;
    }
    __syncthreads();
  }
}

// ---------------- mega kernel ----------------------------------------------
__global__ __launch_bounds__(NTHR,1) void k_mega(
    const float* __restrict__ xyz, const float* __restrict__ features,
    const float* __restrict__ featT, int useT,
    float* __restrict__ newxyz, int* __restrict__ first, CtlBlock* ctl,
    const float* __restrict__ pe1w, const float* __restrict__ pe1b,
    const float* __restrict__ bnsc, const float* __restrict__ bnsh,
    const u16* __restrict__ pe2wb, const float* __restrict__ pe2b,
    const u16* __restrict__ ipwb, const float* __restrict__ ipb,
    const u16* __restrict__ opwb, const float* __restrict__ opb,
    const float* __restrict__ ln1s, const float* __restrict__ ln1b,
    const float* __restrict__ ln2s, const float* __restrict__ ln2b,
    const u16* __restrict__ fc1wb, const float* __restrict__ fc1b,
    const u16* __restrict__ fc2wb, const float* __restrict__ fc2b,
    float* __restrict__ out){
  __shared__ SMem sm;
  const int t = threadIdx.x, lane = t & 63, wid = t >> 6;

  if (blockIdx.x < NB){
    fps_run(blockIdx.x, xyz, newxyz, ctl, sm);
  } else {
    // phase 1: ballq + first-occurrence arbitration, paced by FPS progress
    for (;;){
      if (t==0) sm.misc[1] = atomicAdd(&ctl->ctr1, 1);
      __syncthreads();
      int p = sm.misc[1];
      if (p >= NB*NPp) break;
      int b = p >> 11, pp = p & (NPp-1);
      if (t==0){
        while (__hip_atomic_load(&ctl->prog[b], __ATOMIC_RELAXED, __HIP_MEMORY_SCOPE_AGENT) < pp)
          __builtin_amdgcn_s_sleep(2);
        __builtin_amdgcn_fence(__ATOMIC_ACQUIRE, "agent");
      }
      __syncthreads();
      float cx = newxyz[(size_t)p*3], cy = newxyz[(size_t)p*3+1], cz = newxyz[(size_t)p*3+2];
      seq_ballq(xyz + (size_t)b*NN*3, cx, cy, cz, sm, t, lane, wid);
      if (t < NSs) atomicMin(&first[b*NN + sm.idx_sh[t]], pp*NSs + t);
      __syncthreads();
    }
  }

  // grid barrier (custom, single-use; counter reset by k_prep each launch)
  __syncthreads();
  if (t==0){
    __builtin_amdgcn_fence(__ATOMIC_RELEASE, "agent");
    __hip_atomic_fetch_add(&ctl->bar, 1, __ATOMIC_RELAXED, __HIP_MEMORY_SCOPE_AGENT);
    while (__hip_atomic_load(&ctl->bar, __ATOMIC_RELAXED, __HIP_MEMORY_SCOPE_AGENT) < NBLK)
      __builtin_amdgcn_s_sleep(8);
    __builtin_amdgcn_fence(__ATOMIC_ACQUIRE, "agent");
  }
  __syncthreads();

  // phase 2: recompute winning sequences, write winning rows to out
  for (;;){
    if (t==0) sm.misc[1] = atomicAdd(&ctl->ctr2, 1);
    __syncthreads();
    int p = sm.misc[1];
    if (p >= NB*NPp) break;
    int b = p >> 11, pp = p & (NPp-1);
    float cx = newxyz[(size_t)p*3], cy = newxyz[(size_t)p*3+1], cz = newxyz[(size_t)p*3+2];
    seq_ballq(xyz + (size_t)b*NN*3, cx, cy, cz, sm, t, lane, wid);
    if (t==0) sm.misc[2] = 0;
    __syncthreads();
    if (t < NSs){
      int pos = pp*NSs + t;
      int f = __hip_atomic_load(&first[b*NN + sm.idx_sh[t]], __ATOMIC_RELAXED, __HIP_MEMORY_SCOPE_AGENT);
      int w = (f == pos) ? 1 : 0;
      sm.win[t] = w;
      if (w) atomicOr(&sm.misc[2], 1);
    }
    __syncthreads();
    if (!sm.misc[2]) continue;
    seq_pe_tf(sm, b, p, xyz, features, featT, useT, newxyz,
              pe1w, pe1b, bnsc, bnsh, pe2wb, pe2b, ipwb, ipb, opwb, opb,
              ln1s, ln1b, ln2s, ln2b, fc1wb, fc1b, fc2wb, fc2b);
    for (int e=t; e<NSs*NC; e+=NTHR){
      int s = e >> 8, c = e & 255;
      if (sm.win[s]) out[((size_t)b*NN + sm.idx_sh[s])*NC + c] = sm.xs[s][c];
    }
    __syncthreads();
  }
}

// ---------------- fill unclaimed rows --------------------------------------
__global__ __launch_bounds__(256) void k_outfill_T(const float* __restrict__ featT,
                                                   const int* __restrict__ first,
                                                   float* __restrict__ out){
  const int t = threadIdx.x;
  for (int rr=0; rr<8; ++rr){
    int row = blockIdx.x*8 + rr;
    if (first[row] == LFv)
      out[(size_t)row*NC + t] = featT[(size_t)row*NC + t];
  }
}

__global__ __launch_bounds__(256) void k_outfill_noT(const float* __restrict__ feat,
                                                     const int* __restrict__ first,
                                                     float* __restrict__ out){
  __shared__ float T[32][33];
  const int b = blockIdx.y;
  const int n0 = blockIdx.x*32;
  const int t = threadIdx.x;
  const int tn = t & 31, tc = t >> 5;
  for (int cb=0; cb<NC; cb+=32){
    #pragma unroll
    for (int i=0;i<32;i+=8)
      T[tc+i][tn] = feat[((size_t)b*NC + cb+tc+i)*NN + n0+tn];
    __syncthreads();
    #pragma unroll
    for (int i=0;i<32;i+=8){
      int n = n0 + tc + i;
      if (first[b*NN+n] == LFv)
        out[((size_t)b*NN + n)*NC + cb+tn] = T[tn][tc+i];
    }
    __syncthreads();
  }
}

extern "C" void kernel_launch(void* const* d_in, const int* in_sizes, int n_in,
                              void* d_out, int out_size, void* d_ws, size_t ws_size,
                              hipStream_t stream){
  const float* xyz   = (const float*)d_in[0];
  const float* feat  = (const float*)d_in[1];
  const float* pe1w  = (const float*)d_in[2];
  const float* pe1b  = (const float*)d_in[3];
  const float* bng   = (const float*)d_in[4];
  const float* bnb   = (const float*)d_in[5];
  const float* bnm   = (const float*)d_in[6];
  const float* bnv   = (const float*)d_in[7];
  const float* pe2w  = (const float*)d_in[8];
  const float* pe2b  = (const float*)d_in[9];
  const float* ipw   = (const float*)d_in[10];
  const float* ipb   = (const float*)d_in[11];
  const float* opw   = (const float*)d_in[12];
  const float* opb   = (const float*)d_in[13];
  const float* ln1s  = (const float*)d_in[14];
  const float* ln1b  = (const float*)d_in[15];
  const float* ln2s  = (const float*)d_in[16];
  const float* ln2b  = (const float*)d_in[17];
  const float* fc1w  = (const float*)d_in[18];
  const float* fc1b  = (const float*)d_in[19];
  const float* fc2w  = (const float*)d_in[20];
  const float* fc2b  = (const float*)d_in[21];
  float* out = (float*)d_out;

  char* ws = (char*)d_ws;
  size_t off = 0;
  auto alloc = [&](size_t bytes)->void*{
    void* p = ws + off;
    off = (off + bytes + 255) & ~(size_t)255;
    return p;
  };
  float* newxyz  = (float*)alloc((size_t)NB*NPp*3*4);
  int*   first   = (int*)  alloc((size_t)NB*NN*4);
  CtlBlock* ctl  = (CtlBlock*)alloc(sizeof(CtlBlock));
  float* bnsc    = (float*)alloc(128*4);
  float* bnsh    = (float*)alloc(128*4);
  u16*   ipwb    = (u16*)  alloc((size_t)NL*768*NC*2);
  u16*   opwb    = (u16*)  alloc((size_t)NL*NC*NC*2);
  u16*   fc1wb   = (u16*)  alloc((size_t)NL*NDFF*NC*2);
  u16*   fc2wb   = (u16*)  alloc((size_t)NL*NC*NDFF*2);
  u16*   pe2wb   = (u16*)  alloc((size_t)NC*128*2);
  float* featT   = (float*)(ws + off);
  int useT = (off + (size_t)NB*NN*NC*4 <= ws_size) ? 1 : 0;

  k_prep<<<512, 256, 0, stream>>>(ipw, opw, fc1w, fc2w, pe2w, bng, bnb, bnm, bnv,
                                  ipwb, opwb, fc1wb, fc2wb, pe2wb, bnsc, bnsh, first, ctl);
  if (useT)
    k_featT<<<dim3(NN/32, NB), 256, 0, stream>>>(feat, featT);

  const float* featT_c = featT;
  void* kargs[] = {
    (void*)&xyz, (void*)&feat, (void*)&featT_c, (void*)&useT,
    (void*)&newxyz, (void*)&first, (void*)&ctl,
    (void*)&pe1w, (void*)&pe1b, (void*)&bnsc, (void*)&bnsh,
    (void*)&pe2wb, (void*)&pe2b, (void*)&ipwb, (void*)&ipb,
    (void*)&opwb, (void*)&opb, (void*)&ln1s, (void*)&ln1b,
    (void*)&ln2s, (void*)&ln2b, (void*)&fc1wb, (void*)&fc1b,
    (void*)&fc2wb, (void*)&fc2b, (void*)&out };
  hipLaunchCooperativeKernel((void*)k_mega, dim3(NBLK), dim3(NTHR), kargs, 0, stream);

  if (useT)
    k_outfill_T<<<(NB*NN)/8, 256, 0, stream>>>(featT, first, out);
  else
    k_outfill_noT<<<dim3(NN/32, NB), 256, 0, stream>>>(feat, first, out);
  (void)in_sizes; (void)n_in; (void)out_size;
}